// Round 1
// baseline (930.581 us; speedup 1.0000x reference)
//
#include <hip/hip_runtime.h>
#include <cstdint>
#include <cstddef>

#define N_SP 4096
#define C_IN 512
#define C_QK 64
#define C_V  128

// ---------------- K1: QKV projection ----------------
// Q[b][o][n] = sum_c Wq[o][c] * x[b][c][n] + bq[o]   (rows 0..63)
// K rows 64..127, V rows 128..255. Output layouts: [b][chan][n].
__global__ __launch_bounds__(256) void qkv_kernel(
    const float* __restrict__ x,
    const float* __restrict__ Wq, const float* __restrict__ bq,
    const float* __restrict__ Wk, const float* __restrict__ bk,
    const float* __restrict__ Wv, const float* __restrict__ bv,
    float* __restrict__ Qp, float* __restrict__ Kp, float* __restrict__ Vp)
{
    __shared__ float xs[32][64];    // [c][n] chunk, 8 KB
    __shared__ float wl[32][256];   // [c][orow] chunk, 32 KB
    const int t = threadIdx.x;
    const int b = blockIdx.x & 3;                 // b fastest -> XCD shares batch
    const int n0 = (blockIdx.x >> 2) << 6;        // 64 n per block
    const int og = t >> 4;                        // 16 output rows each
    const int ng = t & 15;                        // 4 n-cols each
    float ax[16], ay[16], az[16], aw[16];
    #pragma unroll
    for (int j = 0; j < 16; ++j) { ax[j] = ay[j] = az[j] = aw[j] = 0.f; }
    const float* xb = x + (size_t)b * C_IN * N_SP;
    const int o = t;  // weight staging: thread t streams weight row o=t
    const float* wsrc = (o < 64) ? (Wq + o * C_IN)
                      : (o < 128) ? (Wk + (o - 64) * C_IN)
                                  : (Wv + (o - 128) * C_IN);
    for (int cc = 0; cc < 16; ++cc) {
        const int c0 = cc << 5;
        for (int idx = t; idx < 512; idx += 256) {
            const int ci = idx >> 4, j4 = (idx & 15) << 2;
            *(float4*)&xs[ci][j4] =
                *(const float4*)(xb + (size_t)(c0 + ci) * N_SP + n0 + j4);
        }
        #pragma unroll 8
        for (int ci = 0; ci < 32; ++ci) wl[ci][o] = wsrc[c0 + ci];
        __syncthreads();
        #pragma unroll 4
        for (int ci = 0; ci < 32; ++ci) {
            const float4 xv = *(const float4*)&xs[ci][ng << 2];
            #pragma unroll
            for (int j = 0; j < 16; ++j) {
                const float w = wl[ci][(og << 4) + j];
                ax[j] += w * xv.x; ay[j] += w * xv.y;
                az[j] += w * xv.z; aw[j] += w * xv.w;
            }
        }
        __syncthreads();
    }
    #pragma unroll
    for (int j = 0; j < 16; ++j) {
        const int oo = (og << 4) + j;   // branch is wave-uniform (64 rows/wave)
        float bias; float* dst;
        if (oo < 64)       { bias = bq[oo];       dst = Qp + (size_t)(b * C_QK + oo) * N_SP; }
        else if (oo < 128) { bias = bk[oo - 64];  dst = Kp + (size_t)(b * C_QK + oo - 64) * N_SP; }
        else               { bias = bv[oo - 128]; dst = Vp + (size_t)(b * C_V + oo - 128) * N_SP; }
        float4 r;
        r.x = ax[j] + bias; r.y = ay[j] + bias;
        r.z = az[j] + bias; r.w = aw[j] + bias;
        *(float4*)(dst + n0 + (ng << 2)) = r;
    }
}

// ---------------- K2: flash attention ----------------
// Per block: 64 query cols (n0..n0+63) of one batch; loop 128 key tiles of 32.
// S[n][m] = sum_c Q[c][n]*K[c][m]; online softmax (stats in registers,
// replicated across each 16-lane row-group); O[n][cv] += P[n][m]*V[cv][m].
__global__ __launch_bounds__(256) void attn_kernel(
    const float* __restrict__ Qp, const float* __restrict__ Kp,
    const float* __restrict__ Vp, float* __restrict__ Op)
{
    __shared__ union U {
        struct S {
            float q[64][64];   // [c][n]
            float k[64][32];   // [c][m]
            float v[128][32];  // [cv][(m + (cv>>3)) & 31]  rotated for bank-free PV reads
            float p[64][33];   // [n][m] (+1 pad)
        } s;
        float ot[64 * 129];    // output transpose staging (aliases q/k/v, all dead)
    } sm;
    const int t = threadIdx.x;
    const int b = blockIdx.x & 3;
    const int n0 = (blockIdx.x >> 2) << 6;
    const int r = t >> 4;      // row group: owns rows 4r..4r+3 (same rows in S and PV)
    const int mg = t & 15;     // S: m = 2*mg,2*mg+1 ; PV: cv = 8*mg..8*mg+7
    const float* Qb = Qp + (size_t)b * C_QK * N_SP;
    const float* Kb = Kp + (size_t)b * C_QK * N_SP;
    const float* Vb = Vp + (size_t)b * C_V * N_SP;

    for (int idx = t; idx < 1024; idx += 256) {
        const int c = idx >> 4, j4 = (idx & 15) << 2;
        *(float4*)&sm.s.q[c][j4] = *(const float4*)(Qb + (size_t)c * N_SP + n0 + j4);
    }
    float oldm[4], lsum[4], accv[4][8];
    #pragma unroll
    for (int i = 0; i < 4; ++i) {
        oldm[i] = -1e30f; lsum[i] = 0.f;
        #pragma unroll
        for (int j = 0; j < 8; ++j) accv[i][j] = 0.f;
    }
    __syncthreads();

    for (int kt = 0; kt < 128; ++kt) {
        const int m0 = kt << 5;
        for (int idx = t; idx < 512; idx += 256) {
            const int c = idx >> 3, j4 = (idx & 7) << 2;
            *(float4*)&sm.s.k[c][j4] = *(const float4*)(Kb + (size_t)c * N_SP + m0 + j4);
        }
        for (int idx = t; idx < 1024; idx += 256) {
            const int cv = idx >> 3, j4 = (idx & 7) << 2;
            const float4 v = *(const float4*)(Vb + (size_t)cv * N_SP + m0 + j4);
            const int rot = cv >> 3;
            sm.s.v[cv][(j4 + rot) & 31]     = v.x;
            sm.s.v[cv][(j4 + 1 + rot) & 31] = v.y;
            sm.s.v[cv][(j4 + 2 + rot) & 31] = v.z;
            sm.s.v[cv][(j4 + 3 + rot) & 31] = v.w;
        }
        __syncthreads();

        // ---- S = Q^T K : per-thread tile [4 rows][2 m] ----
        float s0[4], s1[4];
        #pragma unroll
        for (int i = 0; i < 4; ++i) { s0[i] = 0.f; s1[i] = 0.f; }
        #pragma unroll 4
        for (int c = 0; c < 64; ++c) {
            const float4 qv = *(const float4*)&sm.s.q[c][r << 2];
            const float2 kv = *(const float2*)&sm.s.k[c][mg << 1];
            s0[0] += qv.x * kv.x; s1[0] += qv.x * kv.y;
            s0[1] += qv.y * kv.x; s1[1] += qv.y * kv.y;
            s0[2] += qv.z * kv.x; s1[2] += qv.z * kv.y;
            s0[3] += qv.w * kv.x; s1[3] += qv.w * kv.y;
        }
        // ---- online softmax; stats replicated across the 16-lane group ----
        float al[4];
        #pragma unroll
        for (int i = 0; i < 4; ++i) {
            float tm = fmaxf(s0[i], s1[i]);
            tm = fmaxf(tm, __shfl_xor(tm, 1));
            tm = fmaxf(tm, __shfl_xor(tm, 2));
            tm = fmaxf(tm, __shfl_xor(tm, 4));
            tm = fmaxf(tm, __shfl_xor(tm, 8));
            const float nm = fmaxf(oldm[i], tm);
            al[i] = __expf(oldm[i] - nm);
            const float p0 = __expf(s0[i] - nm);
            const float p1 = __expf(s1[i] - nm);
            oldm[i] = nm;
            sm.s.p[(r << 2) + i][(mg << 1)]     = p0;
            sm.s.p[(r << 2) + i][(mg << 1) + 1] = p1;
            float pp = p0 + p1;
            pp += __shfl_xor(pp, 1);
            pp += __shfl_xor(pp, 2);
            pp += __shfl_xor(pp, 4);
            pp += __shfl_xor(pp, 8);
            lsum[i] = lsum[i] * al[i] + pp;
        }
        // ---- PV: per-thread tile [4 rows][8 cv]; p rows written by own wave ----
        #pragma unroll
        for (int i = 0; i < 4; ++i)
            #pragma unroll
            for (int j = 0; j < 8; ++j) accv[i][j] *= al[i];
        #pragma unroll 2
        for (int m = 0; m < 32; ++m) {
            float pv[4];
            #pragma unroll
            for (int i = 0; i < 4; ++i) pv[i] = sm.s.p[(r << 2) + i][m];
            #pragma unroll
            for (int j = 0; j < 8; ++j) {
                const float vv = sm.s.v[(mg << 3) + j][(m + mg) & 31];
                #pragma unroll
                for (int i = 0; i < 4; ++i) accv[i][j] += pv[i] * vv;
            }
        }
        __syncthreads();
    }

    float inv[4];
    #pragma unroll
    for (int i = 0; i < 4; ++i) inv[i] = 1.0f / lsum[i];
    #pragma unroll
    for (int i = 0; i < 4; ++i)
        #pragma unroll
        for (int j = 0; j < 8; ++j)
            sm.ot[((r << 2) + i) * 129 + (mg << 3) + j] = accv[i][j] * inv[i];
    __syncthreads();
    for (int idx = t; idx < 8192; idx += 256) {
        const int cv = idx >> 6, j = idx & 63;
        Op[(size_t)(b * C_V + cv) * N_SP + n0 + j] = sm.ot[j * 129 + cv];
    }
}

// ---------------- K3: output projection + residual ----------------
// out[b][co][n] = x[b][co][n] + g*(bo[co] + sum_cv Wo[co][cv]*Oa[b][cv][n])
__global__ __launch_bounds__(256) void proj_kernel(
    const float* __restrict__ Oa, const float* __restrict__ Wo,
    const float* __restrict__ bo, const float* __restrict__ x,
    const float* __restrict__ gamma_p, float* __restrict__ out)
{
    __shared__ float ol[128][64];   // [cv][n] 32 KB
    __shared__ float wl[32][128];   // [cv-chunk][co] 16 KB
    const int t = threadIdx.x;
    const int b = blockIdx.x & 3;
    const int coq = (blockIdx.x >> 2) & 3;
    const int n0 = (blockIdx.x >> 4) << 6;
    const int co0 = coq << 7;
    const int og = t >> 4, ng = t & 15;
    for (int idx = t; idx < 2048; idx += 256) {
        const int cv = idx >> 4, j4 = (idx & 15) << 2;
        *(float4*)&ol[cv][j4] =
            *(const float4*)(Oa + (size_t)(b * C_V + cv) * N_SP + n0 + j4);
    }
    float ax[8], ay[8], az[8], aw[8];
    #pragma unroll
    for (int j = 0; j < 8; ++j) ax[j] = ay[j] = az[j] = aw[j] = 0.f;
    for (int cc = 0; cc < 4; ++cc) {
        __syncthreads();   // first: covers ol; later: protects wl re-stage
        for (int idx = t; idx < 4096; idx += 256) {
            const int o = idx & 127, ci = idx >> 7;
            wl[ci][o] = Wo[(size_t)(co0 + o) * C_V + (cc << 5) + ci];
        }
        __syncthreads();
        #pragma unroll 4
        for (int ci = 0; ci < 32; ++ci) {
            const float4 ov = *(const float4*)&ol[(cc << 5) + ci][ng << 2];
            #pragma unroll
            for (int j = 0; j < 8; ++j) {
                const float w = wl[ci][(og << 3) + j];
                ax[j] += w * ov.x; ay[j] += w * ov.y;
                az[j] += w * ov.z; aw[j] += w * ov.w;
            }
        }
    }
    const float g = gamma_p[0];
    #pragma unroll
    for (int j = 0; j < 8; ++j) {
        const int o = co0 + (og << 3) + j;
        const size_t off = (size_t)(b * C_IN + o) * N_SP + n0 + (ng << 2);
        const float4 xv = *(const float4*)(x + off);
        const float bias = bo[o];
        float4 rs;
        rs.x = xv.x + g * (ax[j] + bias);
        rs.y = xv.y + g * (ay[j] + bias);
        rs.z = xv.z + g * (az[j] + bias);
        rs.w = xv.w + g * (aw[j] + bias);
        *(float4*)(out + off) = rs;
    }
}

extern "C" void kernel_launch(void* const* d_in, const int* in_sizes, int n_in,
                              void* d_out, int out_size, void* d_ws, size_t ws_size,
                              hipStream_t stream) {
    (void)in_sizes; (void)n_in; (void)out_size; (void)ws_size;
    const float* x  = (const float*)d_in[0];
    const float* Wq = (const float*)d_in[1];
    const float* bq = (const float*)d_in[2];
    const float* Wk = (const float*)d_in[3];
    const float* bk = (const float*)d_in[4];
    const float* Wv = (const float*)d_in[5];
    const float* bv = (const float*)d_in[6];
    const float* Wo = (const float*)d_in[7];
    const float* bo = (const float*)d_in[8];
    const float* gm = (const float*)d_in[9];
    float* out = (float*)d_out;
    float* ws  = (float*)d_ws;
    // ws layout (floats): Q[4][64][4096] | K[4][64][4096] | V[4][128][4096] | Oa[4][128][4096]
    float* Qp = ws;
    float* Kp = Qp + (size_t)4 * C_QK * N_SP;
    float* Vp = Kp + (size_t)4 * C_QK * N_SP;
    float* Op = Vp + (size_t)4 * C_V * N_SP;
    qkv_kernel<<<256, 256, 0, stream>>>(x, Wq, bq, Wk, bk, Wv, bv, Qp, Kp, Vp);
    attn_kernel<<<256, 256, 0, stream>>>(Qp, Kp, Vp, Op);
    proj_kernel<<<1024, 256, 0, stream>>>(Op, Wo, bo, x, gm, out);
}

// Round 2
// 448.906 us; speedup vs baseline: 2.0730x; 2.0730x over previous
//
#include <hip/hip_runtime.h>
#include <cstdint>
#include <cstddef>

#define N_SP 4096
#define C_IN 512
#define C_QK 64
#define C_V  128

typedef unsigned short u16;
typedef __attribute__((ext_vector_type(8))) short bf16x8;
typedef __attribute__((ext_vector_type(4))) float f32x4;

__device__ __forceinline__ u16 f2bf(float f) {
    union { float f; uint32_t u; } x; x.f = f;
    const uint32_t r = x.u + 0x7fffu + ((x.u >> 16) & 1u);
    return (u16)(r >> 16);
}

// Swizzled pointer into a 128-byte-row LDS tile: byte ^= (row&7)<<4.
// Bijective within each 8-row stripe; keeps 16B alignment for b128 ops.
__device__ __forceinline__ void* swzPtr(void* base, int row, int colByte) {
    return (char*)base + row * 128 + (colByte ^ ((row & 7) << 4));
}

// ---------------- K1: QKV projection (fp32 accum, bf16 outputs) ----------------
// Qb[b][n][64], Kb[b][n][64]  (n-major, MFMA A/B staging layout)
// Vb[b][cv][n]                (cv-major = PV B-operand layout)
__global__ __launch_bounds__(256) void qkv_kernel(
    const float* __restrict__ x,
    const float* __restrict__ Wq, const float* __restrict__ bq,
    const float* __restrict__ Wk, const float* __restrict__ bk,
    const float* __restrict__ Wv, const float* __restrict__ bv,
    u16* __restrict__ Qb, u16* __restrict__ Kb, u16* __restrict__ Vb)
{
    __shared__ union {
        struct { float xs[32][64]; float wl[32][256]; } a;
        u16 tr[64][132];   // epilogue transpose staging for Q/K (aliases xs/wl)
    } sm;
    const int t = threadIdx.x;
    const int b = blockIdx.x & 3;                 // b fastest -> XCD shares batch
    const int n0 = (blockIdx.x >> 2) << 6;        // 64 n per block
    const int og = t >> 4;                        // 16 output rows each
    const int ng = t & 15;                        // 4 n-cols each
    float ax[16], ay[16], az[16], aw[16];
    #pragma unroll
    for (int j = 0; j < 16; ++j) { ax[j] = ay[j] = az[j] = aw[j] = 0.f; }
    const float* xb = x + (size_t)b * C_IN * N_SP;
    const int o = t;  // weight staging: thread t streams weight row o=t
    const float* wsrc = (o < 64) ? (Wq + o * C_IN)
                      : (o < 128) ? (Wk + (o - 64) * C_IN)
                                  : (Wv + (o - 128) * C_IN);
    for (int cc = 0; cc < 16; ++cc) {
        const int c0 = cc << 5;
        for (int idx = t; idx < 512; idx += 256) {
            const int ci = idx >> 4, j4 = (idx & 15) << 2;
            *(float4*)&sm.a.xs[ci][j4] =
                *(const float4*)(xb + (size_t)(c0 + ci) * N_SP + n0 + j4);
        }
        #pragma unroll 8
        for (int ci = 0; ci < 32; ++ci) sm.a.wl[ci][o] = wsrc[c0 + ci];
        __syncthreads();
        #pragma unroll 4
        for (int ci = 0; ci < 32; ++ci) {
            const float4 xv = *(const float4*)&sm.a.xs[ci][ng << 2];
            #pragma unroll
            for (int j = 0; j < 16; ++j) {
                const float w = sm.a.wl[ci][(og << 4) + j];
                ax[j] += w * xv.x; ay[j] += w * xv.y;
                az[j] += w * xv.z; aw[j] += w * xv.w;
            }
        }
        __syncthreads();
    }
    // Epilogue: V rows store directly; Q/K rows transpose via LDS.
    if (og >= 8) {
        #pragma unroll
        for (int j = 0; j < 16; ++j) {
            const int cv = ((og - 8) << 4) + j;
            const float bias = bv[cv];
            ushort4 rv;
            rv.x = f2bf(ax[j] + bias); rv.y = f2bf(ay[j] + bias);
            rv.z = f2bf(az[j] + bias); rv.w = f2bf(aw[j] + bias);
            *(ushort4*)(Vb + ((size_t)(b * C_V + cv) << 12) + n0 + (ng << 2)) = rv;
        }
    } else {
        #pragma unroll
        for (int j = 0; j < 16; ++j) {
            const int oo = (og << 4) + j;
            const float bias = (oo < 64) ? bq[oo] : bk[oo - 64];
            sm.tr[(ng << 2) + 0][oo] = f2bf(ax[j] + bias);
            sm.tr[(ng << 2) + 1][oo] = f2bf(ay[j] + bias);
            sm.tr[(ng << 2) + 2][oo] = f2bf(az[j] + bias);
            sm.tr[(ng << 2) + 3][oo] = f2bf(aw[j] + bias);
        }
    }
    __syncthreads();
    for (int u = t; u < 2048; u += 256) {           // 64 n x 128 ch as ushort4
        const int n = u >> 5, c4 = (u & 31) << 2;
        const ushort4 val = *(const ushort4*)&sm.tr[n][c4];
        if (c4 < 64)
            *(ushort4*)(Qb + ((size_t)(b * N_SP + n0 + n) << 6) + c4) = val;
        else
            *(ushort4*)(Kb + ((size_t)(b * N_SP + n0 + n) << 6) + (c4 - 64)) = val;
    }
}

// ---------------- K2: MFMA flash attention ----------------
// Block: 64 queries, 4 waves (16 q-rows each). Loop 64 key-tiles of 64.
// S = Q·K^T via mfma_16x16x32_bf16 (A=Q rows, B=K rows, same frag pattern);
// online softmax in registers (C/D layout: col=lane&15, row=(lane>>4)*4+reg);
// P -> LDS bf16 -> A-frag; O += P·V with V[cv][key] as B-frag. All LDS tiles
// are 128B-row row-major -> XOR swizzle (row&7)<<4 everywhere.
__global__ __launch_bounds__(256) void attn_kernel(
    const u16* __restrict__ Qb, const u16* __restrict__ Kb,
    const u16* __restrict__ Vb, float* __restrict__ Op)
{
    __shared__ union {
        struct { u16 q[64][64]; u16 k[64][64]; u16 v[128][64]; u16 p[64][64]; } s;
        float ot[128][68];  // epilogue transpose (aliases all, then dead)
    } sm;
    const int t = threadIdx.x;
    const int l = t & 63;
    const int w = t >> 6;
    const int lo = l & 15, hi = l >> 4;
    const int b = blockIdx.x & 3;
    const int n0 = (blockIdx.x >> 2) << 6;

    // stage Q tile [64 q][64 ch]
    {
        const u16* src = Qb + ((size_t)(b * N_SP + n0) << 6);
        for (int u = t; u < 512; u += 256) {
            const int n = u >> 3, cb = (u & 7) << 4;
            *(uint4*)swzPtr(sm.s.q, n, cb) = *(const uint4*)(src + n * 64 + (cb >> 1));
        }
    }
    float oldm[4] = {-1e30f, -1e30f, -1e30f, -1e30f};
    float lsum[4] = {0.f, 0.f, 0.f, 0.f};
    f32x4 oacc[8];
    #pragma unroll
    for (int tj = 0; tj < 8; ++tj) oacc[tj] = (f32x4){0.f, 0.f, 0.f, 0.f};
    __syncthreads();

    // Q A-frags, kept in registers for the whole kernel
    const int qrow = (w << 4) + lo;
    const bf16x8 qf0 = *(const bf16x8*)swzPtr(sm.s.q, qrow, hi << 4);
    const bf16x8 qf1 = *(const bf16x8*)swzPtr(sm.s.q, qrow, 64 + (hi << 4));

    const u16* kbase = Kb + ((size_t)b * N_SP << 6);
    const u16* vbase = Vb + ((size_t)(b * C_V) << 12);

    for (int kt = 0; kt < 64; ++kt) {
        const int m0 = kt << 6;
        const u16* ksrc = kbase + ((size_t)m0 << 6);
        for (int u = t; u < 512; u += 256) {
            const int kr = u >> 3, cb = (u & 7) << 4;
            *(uint4*)swzPtr(sm.s.k, kr, cb) = *(const uint4*)(ksrc + kr * 64 + (cb >> 1));
        }
        for (int u = t; u < 1024; u += 256) {
            const int cv = u >> 3, cb = (u & 7) << 4;
            *(uint4*)swzPtr(sm.s.v, cv, cb) =
                *(const uint4*)(vbase + ((size_t)cv << 12) + m0 + (cb >> 1));
        }
        __syncthreads();

        // ---- S = Q·K^T : 4 col-tiles x 2 k-steps ----
        f32x4 sacc[4];
        #pragma unroll
        for (int ti = 0; ti < 4; ++ti) {
            const int krow = (ti << 4) + lo;
            const bf16x8 kb0 = *(const bf16x8*)swzPtr(sm.s.k, krow, hi << 4);
            const bf16x8 kb1 = *(const bf16x8*)swzPtr(sm.s.k, krow, 64 + (hi << 4));
            f32x4 z = (f32x4){0.f, 0.f, 0.f, 0.f};
            z = __builtin_amdgcn_mfma_f32_16x16x32_bf16(qf0, kb0, z, 0, 0, 0);
            sacc[ti] = __builtin_amdgcn_mfma_f32_16x16x32_bf16(qf1, kb1, z, 0, 0, 0);
        }
        // ---- online softmax, stats in registers ----
        float al[4];
        #pragma unroll
        for (int r = 0; r < 4; ++r) {
            float m = fmaxf(fmaxf(sacc[0][r], sacc[1][r]), fmaxf(sacc[2][r], sacc[3][r]));
            m = fmaxf(m, __shfl_xor(m, 1));
            m = fmaxf(m, __shfl_xor(m, 2));
            m = fmaxf(m, __shfl_xor(m, 4));
            m = fmaxf(m, __shfl_xor(m, 8));
            const float nm = fmaxf(oldm[r], m);
            al[r] = __expf(oldm[r] - nm);
            oldm[r] = nm;
            const int prow = (w << 4) + (hi << 2) + r;
            float ps = 0.f;
            #pragma unroll
            for (int ti = 0; ti < 4; ++ti) {
                const float p = __expf(sacc[ti][r] - nm);
                ps += p;
                *(u16*)swzPtr(sm.s.p, prow, ((ti << 4) + lo) << 1) = f2bf(p);
            }
            ps += __shfl_xor(ps, 1);
            ps += __shfl_xor(ps, 2);
            ps += __shfl_xor(ps, 4);
            ps += __shfl_xor(ps, 8);
            lsum[r] = lsum[r] * al[r] + ps;
        }
        // own-wave P rows written above; order LDS write->read (rule 18)
        asm volatile("s_waitcnt lgkmcnt(0)" ::: "memory");
        __builtin_amdgcn_sched_barrier(0);

        // ---- O += P·V : 8 cv-tiles x 2 k-steps ----
        const bf16x8 pa0 = *(const bf16x8*)swzPtr(sm.s.p, qrow, hi << 4);
        const bf16x8 pa1 = *(const bf16x8*)swzPtr(sm.s.p, qrow, 64 + (hi << 4));
        #pragma unroll
        for (int tj = 0; tj < 8; ++tj) {
            #pragma unroll
            for (int r = 0; r < 4; ++r) oacc[tj][r] *= al[r];
            const int vrow = (tj << 4) + lo;
            const bf16x8 vb0 = *(const bf16x8*)swzPtr(sm.s.v, vrow, hi << 4);
            const bf16x8 vb1 = *(const bf16x8*)swzPtr(sm.s.v, vrow, 64 + (hi << 4));
            oacc[tj] = __builtin_amdgcn_mfma_f32_16x16x32_bf16(pa0, vb0, oacc[tj], 0, 0, 0);
            oacc[tj] = __builtin_amdgcn_mfma_f32_16x16x32_bf16(pa1, vb1, oacc[tj], 0, 0, 0);
        }
        __syncthreads();   // protect K/V/P restage next tile
    }

    // ---- epilogue: normalize, transpose via LDS, coalesced fp32 store ----
    float inv[4];
    #pragma unroll
    for (int r = 0; r < 4; ++r) inv[r] = 1.0f / lsum[r];
    #pragma unroll
    for (int tj = 0; tj < 8; ++tj) {
        const int cv = (tj << 4) + lo;
        #pragma unroll
        for (int r = 0; r < 4; ++r)
            sm.ot[cv][(w << 4) + (hi << 2) + r] = oacc[tj][r] * inv[r];
    }
    __syncthreads();
    float* dst = Op + ((size_t)(b * C_V) << 12) + n0;
    for (int u = t; u < 2048; u += 256) {
        const int cv = u >> 4, c4 = (u & 15) << 2;
        *(float4*)(dst + ((size_t)cv << 12) + c4) = *(const float4*)&sm.ot[cv][c4];
    }
}

// ---------------- K3: output projection + residual (unchanged) ----------------
__global__ __launch_bounds__(256) void proj_kernel(
    const float* __restrict__ Oa, const float* __restrict__ Wo,
    const float* __restrict__ bo, const float* __restrict__ x,
    const float* __restrict__ gamma_p, float* __restrict__ out)
{
    __shared__ float ol[128][64];   // [cv][n] 32 KB
    __shared__ float wl[32][128];   // [cv-chunk][co] 16 KB
    const int t = threadIdx.x;
    const int b = blockIdx.x & 3;
    const int coq = (blockIdx.x >> 2) & 3;
    const int n0 = (blockIdx.x >> 4) << 6;
    const int co0 = coq << 7;
    const int og = t >> 4, ng = t & 15;
    for (int idx = t; idx < 2048; idx += 256) {
        const int cv = idx >> 4, j4 = (idx & 15) << 2;
        *(float4*)&ol[cv][j4] =
            *(const float4*)(Oa + (size_t)(b * C_V + cv) * N_SP + n0 + j4);
    }
    float ax[8], ay[8], az[8], aw[8];
    #pragma unroll
    for (int j = 0; j < 8; ++j) ax[j] = ay[j] = az[j] = aw[j] = 0.f;
    for (int cc = 0; cc < 4; ++cc) {
        __syncthreads();   // first: covers ol; later: protects wl re-stage
        for (int idx = t; idx < 4096; idx += 256) {
            const int o = idx & 127, ci = idx >> 7;
            wl[ci][o] = Wo[(size_t)(co0 + o) * C_V + (cc << 5) + ci];
        }
        __syncthreads();
        #pragma unroll 4
        for (int ci = 0; ci < 32; ++ci) {
            const float4 ov = *(const float4*)&ol[(cc << 5) + ci][ng << 2];
            #pragma unroll
            for (int j = 0; j < 8; ++j) {
                const float w = wl[ci][(og << 3) + j];
                ax[j] += w * ov.x; ay[j] += w * ov.y;
                az[j] += w * ov.z; aw[j] += w * ov.w;
            }
        }
    }
    const float g = gamma_p[0];
    #pragma unroll
    for (int j = 0; j < 8; ++j) {
        const int o = co0 + (og << 3) + j;
        const size_t off = (size_t)(b * C_IN + o) * N_SP + n0 + (ng << 2);
        const float4 xv = *(const float4*)(x + off);
        const float bias = bo[o];
        float4 rs;
        rs.x = xv.x + g * (ax[j] + bias);
        rs.y = xv.y + g * (ay[j] + bias);
        rs.z = xv.z + g * (az[j] + bias);
        rs.w = xv.w + g * (aw[j] + bias);
        *(float4*)(out + off) = rs;
    }
}

extern "C" void kernel_launch(void* const* d_in, const int* in_sizes, int n_in,
                              void* d_out, int out_size, void* d_ws, size_t ws_size,
                              hipStream_t stream) {
    (void)in_sizes; (void)n_in; (void)out_size; (void)ws_size;
    const float* x  = (const float*)d_in[0];
    const float* Wq = (const float*)d_in[1];
    const float* bq = (const float*)d_in[2];
    const float* Wk = (const float*)d_in[3];
    const float* bk = (const float*)d_in[4];
    const float* Wv = (const float*)d_in[5];
    const float* bv = (const float*)d_in[6];
    const float* Wo = (const float*)d_in[7];
    const float* bo = (const float*)d_in[8];
    const float* gm = (const float*)d_in[9];
    float* out = (float*)d_out;
    // ws layout: Qb[4][4096][64] bf16 | Kb[4][4096][64] bf16 | Vb[4][128][4096] bf16 | Op[4][128][4096] f32
    u16* Qb = (u16*)d_ws;
    u16* Kb = Qb + (size_t)4 * N_SP * C_QK;
    u16* Vb = Kb + (size_t)4 * N_SP * C_QK;
    float* Op = (float*)(Vb + (size_t)4 * C_V * N_SP);
    qkv_kernel<<<256, 256, 0, stream>>>(x, Wq, bq, Wk, bk, Wv, bv, Qb, Kb, Vb);
    attn_kernel<<<256, 256, 0, stream>>>(Qb, Kb, Vb, Op);
    proj_kernel<<<1024, 256, 0, stream>>>(Op, Wo, bo, x, gm, out);
}

// Round 3
// 160.999 us; speedup vs baseline: 5.7800x; 2.7883x over previous
//
#include <hip/hip_runtime.h>
#include <cstdint>
#include <cstddef>

#define N_SP 4096
#define C_IN 512
#define C_QK 64
#define C_V  128

typedef unsigned short u16;
typedef __attribute__((ext_vector_type(8))) short bf16x8;
typedef __attribute__((ext_vector_type(4))) float f32x4;

__device__ __forceinline__ u16 f2bf(float f) {
    union { float f; uint32_t u; } x; x.f = f;
    const uint32_t r = x.u + 0x7fffu + ((x.u >> 16) & 1u);
    return (u16)(r >> 16);
}
__device__ __forceinline__ float bf2f(u16 b) {
    union { uint32_t u; float f; } x; x.u = ((uint32_t)b) << 16;
    return x.f;
}

// Swizzled pointer into a 128-byte-row LDS tile: byte ^= (row&7)<<4.
__device__ __forceinline__ void* swzPtr(void* base, int row, int colByte) {
    return (char*)base + row * 128 + (colByte ^ ((row & 7) << 4));
}

// ---------------- K0: transpose-convert x[b][c][n] f32 -> xb[b][n][c] bf16 ----
// Tile [64 c][64 n]. LDS swizzle XOR ((c>>3)&7)<<4: write phase ~2-4way,
// read phase (8 lanes x 8 scalar c-reads per n-row) conflict-free (2/bank).
__global__ __launch_bounds__(256) void transpose_kernel(
    const float* __restrict__ x, u16* __restrict__ xb)
{
    __shared__ u16 ts[64 * 64];
    const int t = threadIdx.x;
    const int b  = blockIdx.x & 3;
    const int cc = (blockIdx.x >> 2) & 7;
    const int nc = blockIdx.x >> 5;
    const int c0 = cc << 6, n0 = nc << 6;
    const float* xs = x + ((size_t)(b * C_IN + c0) << 12) + n0;
    for (int u = t; u < 1024; u += 256) {
        const int c = u >> 4, nq = (u & 15) << 2;
        const float4 v = *(const float4*)(xs + ((size_t)c << 12) + nq);
        ushort4 h;
        h.x = f2bf(v.x); h.y = f2bf(v.y); h.z = f2bf(v.z); h.w = f2bf(v.w);
        *(ushort4*)((char*)ts + c * 128 + ((nq << 1) ^ (((c >> 3) & 7) << 4))) = h;
    }
    __syncthreads();
    for (int u = t; u < 512; u += 256) {
        const int n = u >> 3, cg = u & 7;
        u16 pk[8];
        #pragma unroll
        for (int j = 0; j < 8; ++j) {
            const int c = (cg << 3) + j;
            pk[j] = *(const u16*)((char*)ts + c * 128 + ((n << 1) ^ (cg << 4)));
        }
        *(ushort4*)(xb + ((size_t)((b << 12) + n0 + n) << 9) + c0 + (cg << 3)) =
            *(ushort4*)&pk[0];
        *(ushort4*)(xb + ((size_t)((b << 12) + n0 + n) << 9) + c0 + (cg << 3) + 4) =
            *(ushort4*)&pk[4];
    }
}

// ---------------- K1: QKV projection, bf16 MFMA ----------------
// Per block: o-tile of 64 (ot: 0=Q,1=K,2/3=V halves) x 64 n, K=512 in 8 chunks.
// ot<2: mfma(A=xb n-rows, B=W o-rows) -> D row=n, col=o -> Qb/Kb[n][64] direct.
// ot>=2: mfma(A=W cv-rows, B=xb n-rows) -> D row=cv, col=n -> Vb[cv][n] direct.
__global__ __launch_bounds__(256) void qkv_kernel(
    const u16* __restrict__ xb,
    const float* __restrict__ Wq, const float* __restrict__ bq,
    const float* __restrict__ Wk, const float* __restrict__ bk,
    const float* __restrict__ Wv, const float* __restrict__ bv,
    u16* __restrict__ Qb, u16* __restrict__ Kb, u16* __restrict__ Vb)
{
    __shared__ u16 wt[64 * 64];   // W chunk  [o][64 c]
    __shared__ u16 xt[64 * 64];   // xb chunk [n][64 c]
    const int t = threadIdx.x;
    const int l = t & 63, w = t >> 6;
    const int lo = l & 15, hi = l >> 4;
    const int b  = blockIdx.x & 3;
    const int ot = (blockIdx.x >> 2) & 3;
    const int n0 = (blockIdx.x >> 4) << 6;
    const float* Wbase = (ot == 0) ? Wq : (ot == 1) ? Wk : (Wv + ((ot - 2) << 6) * C_IN);
    f32x4 acc[4];
    #pragma unroll
    for (int ti = 0; ti < 4; ++ti) acc[ti] = (f32x4){0.f, 0.f, 0.f, 0.f};

    for (int cc = 0; cc < 8; ++cc) {
        const int c0 = cc << 6;
        for (int u = t; u < 1024; u += 256) {      // W rows -> bf16
            const int i = u >> 4, c4 = (u & 15) << 2;
            const float4 v = *(const float4*)(Wbase + (size_t)i * C_IN + c0 + c4);
            ushort4 h;
            h.x = f2bf(v.x); h.y = f2bf(v.y); h.z = f2bf(v.z); h.w = f2bf(v.w);
            *(ushort4*)swzPtr(wt, i, c4 << 1) = h;
        }
        for (int u = t; u < 512; u += 256) {       // xb rows (already bf16)
            const int i = u >> 3, cb = (u & 7) << 4;
            *(uint4*)swzPtr(xt, i, cb) =
                *(const uint4*)(xb + ((size_t)((b << 12) + n0 + i) << 9) + c0 + (cb >> 1));
        }
        __syncthreads();
        if (ot < 2) {
            const bf16x8 af0 = *(const bf16x8*)swzPtr(xt, (w << 4) + lo, hi << 4);
            const bf16x8 af1 = *(const bf16x8*)swzPtr(xt, (w << 4) + lo, 64 + (hi << 4));
            #pragma unroll
            for (int ti = 0; ti < 4; ++ti) {
                const bf16x8 bf0 = *(const bf16x8*)swzPtr(wt, (ti << 4) + lo, hi << 4);
                const bf16x8 bf1 = *(const bf16x8*)swzPtr(wt, (ti << 4) + lo, 64 + (hi << 4));
                acc[ti] = __builtin_amdgcn_mfma_f32_16x16x32_bf16(af0, bf0, acc[ti], 0, 0, 0);
                acc[ti] = __builtin_amdgcn_mfma_f32_16x16x32_bf16(af1, bf1, acc[ti], 0, 0, 0);
            }
        } else {
            const bf16x8 af0 = *(const bf16x8*)swzPtr(wt, (w << 4) + lo, hi << 4);
            const bf16x8 af1 = *(const bf16x8*)swzPtr(wt, (w << 4) + lo, 64 + (hi << 4));
            #pragma unroll
            for (int ti = 0; ti < 4; ++ti) {
                const bf16x8 bf0 = *(const bf16x8*)swzPtr(xt, (ti << 4) + lo, hi << 4);
                const bf16x8 bf1 = *(const bf16x8*)swzPtr(xt, (ti << 4) + lo, 64 + (hi << 4));
                acc[ti] = __builtin_amdgcn_mfma_f32_16x16x32_bf16(af0, bf0, acc[ti], 0, 0, 0);
                acc[ti] = __builtin_amdgcn_mfma_f32_16x16x32_bf16(af1, bf1, acc[ti], 0, 0, 0);
            }
        }
        __syncthreads();
    }
    if (ot < 2) {   // D row = n_local, col = o_local -> [n][64ch]
        const float* bias_base = (ot == 0) ? bq : bk;
        u16* dst = (ot == 0) ? Qb : Kb;
        #pragma unroll
        for (int ti = 0; ti < 4; ++ti) {
            const float bias = bias_base[(ti << 4) + lo];
            #pragma unroll
            for (int r = 0; r < 4; ++r) {
                const int nrow = (w << 4) + (hi << 2) + r;
                dst[((size_t)((b << 12) + n0 + nrow) << 6) + (ti << 4) + lo] =
                    f2bf(acc[ti][r] + bias);
            }
        }
    } else {        // D row = cv_local, col = n_local -> [cv][n]
        #pragma unroll
        for (int r = 0; r < 4; ++r) {
            const int cv = ((ot - 2) << 6) + (w << 4) + (hi << 2) + r;
            const float bias = bv[cv];
            #pragma unroll
            for (int ti = 0; ti < 4; ++ti)
                Vb[((size_t)(b * C_V + cv) << 12) + n0 + (ti << 4) + lo] =
                    f2bf(acc[ti][r] + bias);
        }
    }
}

// ---------------- K2: MFMA flash attention, KV-split x4 ----------------
// Block (b, split s, q-chunk 64): 16 KV tiles of 64. Emits unnormalized
// partial O (bf16) + running m,l per q-row.
__global__ __launch_bounds__(256) void attn_kernel(
    const u16* __restrict__ Qb, const u16* __restrict__ Kb,
    const u16* __restrict__ Vb, u16* __restrict__ po,
    float* __restrict__ pm, float* __restrict__ pl)
{
    __shared__ struct { u16 q[64][64]; u16 k[64][64]; u16 v[128][64]; u16 p[64][64]; } sm;
    const int t = threadIdx.x;
    const int l = t & 63, w = t >> 6;
    const int lo = l & 15, hi = l >> 4;
    const int b = blockIdx.x & 3;
    const int s = (blockIdx.x >> 2) & 3;
    const int n0 = (blockIdx.x >> 4) << 6;
    {
        const u16* src = Qb + ((size_t)((b << 12) + n0) << 6);
        for (int u = t; u < 512; u += 256) {
            const int n = u >> 3, cb = (u & 7) << 4;
            *(uint4*)swzPtr(sm.q, n, cb) = *(const uint4*)(src + n * 64 + (cb >> 1));
        }
    }
    float oldm[4] = {-1e30f, -1e30f, -1e30f, -1e30f};
    float lsum[4] = {0.f, 0.f, 0.f, 0.f};
    f32x4 oacc[8];
    #pragma unroll
    for (int tj = 0; tj < 8; ++tj) oacc[tj] = (f32x4){0.f, 0.f, 0.f, 0.f};
    __syncthreads();

    const int qrow = (w << 4) + lo;
    const bf16x8 qf0 = *(const bf16x8*)swzPtr(sm.q, qrow, hi << 4);
    const bf16x8 qf1 = *(const bf16x8*)swzPtr(sm.q, qrow, 64 + (hi << 4));
    const u16* kbase = Kb + ((size_t)b << 18);
    const u16* vbase = Vb + ((size_t)(b * C_V) << 12);

    for (int kt = s << 4; kt < (s << 4) + 16; ++kt) {
        const int m0 = kt << 6;
        const u16* ksrc = kbase + ((size_t)m0 << 6);
        for (int u = t; u < 512; u += 256) {
            const int kr = u >> 3, cb = (u & 7) << 4;
            *(uint4*)swzPtr(sm.k, kr, cb) = *(const uint4*)(ksrc + kr * 64 + (cb >> 1));
        }
        for (int u = t; u < 1024; u += 256) {
            const int cv = u >> 3, cb = (u & 7) << 4;
            *(uint4*)swzPtr(sm.v, cv, cb) =
                *(const uint4*)(vbase + ((size_t)cv << 12) + m0 + (cb >> 1));
        }
        __syncthreads();

        f32x4 sacc[4];
        #pragma unroll
        for (int ti = 0; ti < 4; ++ti) {
            const int krow = (ti << 4) + lo;
            const bf16x8 kb0 = *(const bf16x8*)swzPtr(sm.k, krow, hi << 4);
            const bf16x8 kb1 = *(const bf16x8*)swzPtr(sm.k, krow, 64 + (hi << 4));
            f32x4 z = (f32x4){0.f, 0.f, 0.f, 0.f};
            z = __builtin_amdgcn_mfma_f32_16x16x32_bf16(qf0, kb0, z, 0, 0, 0);
            sacc[ti] = __builtin_amdgcn_mfma_f32_16x16x32_bf16(qf1, kb1, z, 0, 0, 0);
        }
        float al[4];
        #pragma unroll
        for (int r = 0; r < 4; ++r) {
            float m = fmaxf(fmaxf(sacc[0][r], sacc[1][r]), fmaxf(sacc[2][r], sacc[3][r]));
            m = fmaxf(m, __shfl_xor(m, 1));
            m = fmaxf(m, __shfl_xor(m, 2));
            m = fmaxf(m, __shfl_xor(m, 4));
            m = fmaxf(m, __shfl_xor(m, 8));
            const float nm = fmaxf(oldm[r], m);
            al[r] = __expf(oldm[r] - nm);
            oldm[r] = nm;
            const int prow = (w << 4) + (hi << 2) + r;
            float ps = 0.f;
            #pragma unroll
            for (int ti = 0; ti < 4; ++ti) {
                const float p = __expf(sacc[ti][r] - nm);
                ps += p;
                *(u16*)swzPtr(sm.p, prow, ((ti << 4) + lo) << 1) = f2bf(p);
            }
            ps += __shfl_xor(ps, 1);
            ps += __shfl_xor(ps, 2);
            ps += __shfl_xor(ps, 4);
            ps += __shfl_xor(ps, 8);
            lsum[r] = lsum[r] * al[r] + ps;
        }
        asm volatile("s_waitcnt lgkmcnt(0)" ::: "memory");
        __builtin_amdgcn_sched_barrier(0);

        const bf16x8 pa0 = *(const bf16x8*)swzPtr(sm.p, qrow, hi << 4);
        const bf16x8 pa1 = *(const bf16x8*)swzPtr(sm.p, qrow, 64 + (hi << 4));
        #pragma unroll
        for (int tj = 0; tj < 8; ++tj) {
            #pragma unroll
            for (int r = 0; r < 4; ++r) oacc[tj][r] *= al[r];
            const int vrow = (tj << 4) + lo;
            const bf16x8 vb0 = *(const bf16x8*)swzPtr(sm.v, vrow, hi << 4);
            const bf16x8 vb1 = *(const bf16x8*)swzPtr(sm.v, vrow, 64 + (hi << 4));
            oacc[tj] = __builtin_amdgcn_mfma_f32_16x16x32_bf16(pa0, vb0, oacc[tj], 0, 0, 0);
            oacc[tj] = __builtin_amdgcn_mfma_f32_16x16x32_bf16(pa1, vb1, oacc[tj], 0, 0, 0);
        }
        __syncthreads();
    }
    // partial epilogue: unnormalized O -> bf16, stats per q-row
    u16* pod = po + ((size_t)blockIdx.x << 13);
    #pragma unroll
    for (int tj = 0; tj < 8; ++tj)
        #pragma unroll
        for (int r = 0; r < 4; ++r) {
            const int q = (w << 4) + (hi << 2) + r;
            pod[(q << 7) + (tj << 4) + lo] = f2bf(oacc[tj][r]);
        }
    if (lo == 0) {
        #pragma unroll
        for (int r = 0; r < 4; ++r) {
            const int q = (w << 4) + (hi << 2) + r;
            pm[(blockIdx.x << 6) + q] = oldm[r];
            pl[(blockIdx.x << 6) + q] = lsum[r];
        }
    }
}

// ---------------- K2b: flash combine (4 splits) -> Ob[b][n][cv] bf16 ----------
__global__ __launch_bounds__(256) void combine_kernel(
    const u16* __restrict__ po, const float* __restrict__ pm,
    const float* __restrict__ pl, u16* __restrict__ Ob)
{
    __shared__ float fs[4][64];
    __shared__ float invl[64];
    const int t = threadIdx.x;
    const int b = blockIdx.x & 3;
    const int qc = blockIdx.x >> 2;
    const int n0 = qc << 6;
    int slot[4];
    #pragma unroll
    for (int s = 0; s < 4; ++s) slot[s] = (qc << 4) + (s << 2) + b;
    if (t < 64) {
        float m0 = pm[(slot[0] << 6) + t], m1 = pm[(slot[1] << 6) + t];
        float m2 = pm[(slot[2] << 6) + t], m3 = pm[(slot[3] << 6) + t];
        const float mg = fmaxf(fmaxf(m0, m1), fmaxf(m2, m3));
        const float f0 = __expf(m0 - mg), f1 = __expf(m1 - mg);
        const float f2 = __expf(m2 - mg), f3 = __expf(m3 - mg);
        const float lg = pl[(slot[0] << 6) + t] * f0 + pl[(slot[1] << 6) + t] * f1 +
                         pl[(slot[2] << 6) + t] * f2 + pl[(slot[3] << 6) + t] * f3;
        fs[0][t] = f0; fs[1][t] = f1; fs[2][t] = f2; fs[3][t] = f3;
        invl[t] = 1.0f / lg;
    }
    __syncthreads();
    for (int u = t; u < 2048; u += 256) {
        const int q = u >> 5, c4 = (u & 31) << 2;
        float a0 = 0.f, a1 = 0.f, a2 = 0.f, a3 = 0.f;
        #pragma unroll
        for (int s = 0; s < 4; ++s) {
            const ushort4 h = *(const ushort4*)(po + ((size_t)slot[s] << 13) + (q << 7) + c4);
            const float f = fs[s][q];
            a0 += bf2f(h.x) * f; a1 += bf2f(h.y) * f;
            a2 += bf2f(h.z) * f; a3 += bf2f(h.w) * f;
        }
        const float il = invl[q];
        ushort4 o;
        o.x = f2bf(a0 * il); o.y = f2bf(a1 * il);
        o.z = f2bf(a2 * il); o.w = f2bf(a3 * il);
        *(ushort4*)(Ob + ((size_t)((b << 12) + n0 + q) << 7) + c4) = o;
    }
}

// ---------------- K3: output projection + residual, bf16 MFMA ----------------
// Per block: 64 co x 64 n, K=128 (staged once as 2x64 chunks).
__global__ __launch_bounds__(256) void proj_kernel(
    const u16* __restrict__ Ob, const float* __restrict__ Wo,
    const float* __restrict__ bo, const float* __restrict__ x,
    const float* __restrict__ gamma_p, float* __restrict__ out)
{
    __shared__ union {
        struct { u16 wl0[64 * 64]; u16 wl1[64 * 64]; u16 ob0[64 * 64]; u16 ob1[64 * 64]; } s;
        float tr[64 * 64];   // f32 epilogue transpose, (row>>2)&3 swizzle
    } sm;
    const int t = threadIdx.x;
    const int l = t & 63, w = t >> 6;
    const int lo = l & 15, hi = l >> 4;
    const int b  = blockIdx.x & 3;
    const int co0 = ((blockIdx.x >> 2) & 7) << 6;
    const int n0  = (blockIdx.x >> 5) << 6;
    for (int u = t; u < 2048; u += 256) {          // Wo rows -> bf16 halves
        const int i = u >> 5, c4 = (u & 31) << 2;
        const float4 v = *(const float4*)(Wo + (size_t)(co0 + i) * C_V + c4);
        ushort4 h;
        h.x = f2bf(v.x); h.y = f2bf(v.y); h.z = f2bf(v.z); h.w = f2bf(v.w);
        *(ushort4*)swzPtr((c4 < 64) ? sm.s.wl0 : sm.s.wl1, i, (c4 & 63) << 1) = h;
    }
    for (int u = t; u < 1024; u += 256) {          // Ob rows (bf16) halves
        const int i = u >> 4, cb = (u & 15) << 4;
        *(uint4*)swzPtr((cb < 128) ? sm.s.ob0 : sm.s.ob1, i, cb & 127) =
            *(const uint4*)(Ob + ((size_t)((b << 12) + n0 + i) << 7) + (cb >> 1));
    }
    __syncthreads();
    const int arow = (w << 4) + lo;
    const bf16x8 af00 = *(const bf16x8*)swzPtr(sm.s.wl0, arow, hi << 4);
    const bf16x8 af01 = *(const bf16x8*)swzPtr(sm.s.wl0, arow, 64 + (hi << 4));
    const bf16x8 af10 = *(const bf16x8*)swzPtr(sm.s.wl1, arow, hi << 4);
    const bf16x8 af11 = *(const bf16x8*)swzPtr(sm.s.wl1, arow, 64 + (hi << 4));
    f32x4 acc[4];
    #pragma unroll
    for (int ti = 0; ti < 4; ++ti) {
        const int brow = (ti << 4) + lo;
        f32x4 z = (f32x4){0.f, 0.f, 0.f, 0.f};
        z = __builtin_amdgcn_mfma_f32_16x16x32_bf16(af00, *(const bf16x8*)swzPtr(sm.s.ob0, brow, hi << 4), z, 0, 0, 0);
        z = __builtin_amdgcn_mfma_f32_16x16x32_bf16(af01, *(const bf16x8*)swzPtr(sm.s.ob0, brow, 64 + (hi << 4)), z, 0, 0, 0);
        z = __builtin_amdgcn_mfma_f32_16x16x32_bf16(af10, *(const bf16x8*)swzPtr(sm.s.ob1, brow, hi << 4), z, 0, 0, 0);
        acc[ti] = __builtin_amdgcn_mfma_f32_16x16x32_bf16(af11, *(const bf16x8*)swzPtr(sm.s.ob1, brow, 64 + (hi << 4)), z, 0, 0, 0);
    }
    __syncthreads();   // LDS reuse as f32 tile
    #pragma unroll
    for (int ti = 0; ti < 4; ++ti)
        #pragma unroll
        for (int r = 0; r < 4; ++r) {
            const int co = (w << 4) + (hi << 2) + r;
            const int n  = (ti << 4) + lo;
            sm.tr[(co << 6) + (n ^ (((co >> 2) & 3) << 2))] = acc[ti][r];
        }
    __syncthreads();
    const float g = gamma_p[0];
    for (int u = t; u < 1024; u += 256) {
        const int co = u >> 4, n4 = (u & 15) << 2;
        const float4 av = *(const float4*)&sm.tr[(co << 6) + (n4 ^ (((co >> 2) & 3) << 2))];
        const int o = co0 + co;
        const size_t off = ((size_t)(b * C_IN + o) << 12) + n0 + n4;
        const float4 xv = *(const float4*)(x + off);
        const float bias = bo[o];
        float4 rs;
        rs.x = xv.x + g * (av.x + bias);
        rs.y = xv.y + g * (av.y + bias);
        rs.z = xv.z + g * (av.z + bias);
        rs.w = xv.w + g * (av.w + bias);
        *(float4*)(out + off) = rs;
    }
}

extern "C" void kernel_launch(void* const* d_in, const int* in_sizes, int n_in,
                              void* d_out, int out_size, void* d_ws, size_t ws_size,
                              hipStream_t stream) {
    (void)in_sizes; (void)n_in; (void)out_size; (void)ws_size;
    const float* x  = (const float*)d_in[0];
    const float* Wq = (const float*)d_in[1];
    const float* bq = (const float*)d_in[2];
    const float* Wk = (const float*)d_in[3];
    const float* bk = (const float*)d_in[4];
    const float* Wv = (const float*)d_in[5];
    const float* bv = (const float*)d_in[6];
    const float* Wo = (const float*)d_in[7];
    const float* bo = (const float*)d_in[8];
    const float* gm = (const float*)d_in[9];
    float* out = (float*)d_out;
    // ws layout (bytes): [0,16M): xb bf16 (K0->K1) ALIASED with po bf16 (K2->K2b)
    //   then Qb 2M | Kb 2M | Vb 4M | pm 256K | pl 256K | Ob 4M   (~28.5 MB total)
    u16* xb = (u16*)d_ws;
    u16* po = (u16*)d_ws;                        // alias: xb dead after K1
    u16* Qb = xb + (size_t)8 * 1024 * 1024;
    u16* Kb = Qb + (size_t)4 * N_SP * C_QK;
    u16* Vb = Kb + (size_t)4 * N_SP * C_QK;
    float* pm = (float*)(Vb + (size_t)4 * C_V * N_SP);
    float* pl = pm + 1024 * 64;
    u16* Ob = (u16*)(pl + 1024 * 64);
    transpose_kernel<<<2048, 256, 0, stream>>>(x, xb);
    qkv_kernel<<<1024, 256, 0, stream>>>(xb, Wq, bq, Wk, bk, Wv, bv, Qb, Kb, Vb);
    attn_kernel<<<1024, 256, 0, stream>>>(Qb, Kb, Vb, po, pm, pl);
    combine_kernel<<<256, 256, 0, stream>>>(po, pm, pl, Ob);
    proj_kernel<<<2048, 256, 0, stream>>>(Ob, Wo, bo, x, gm, out);
}

// Round 4
// 126.566 us; speedup vs baseline: 7.3525x; 1.2721x over previous
//
#include <hip/hip_runtime.h>
#include <cstdint>
#include <cstddef>

#define N_SP 4096
#define C_IN 512
#define C_QK 64
#define C_V  128
#define LOG2E 1.4426950408889634f

typedef unsigned short u16;
typedef __attribute__((ext_vector_type(8))) short bf16x8;
typedef __attribute__((ext_vector_type(4))) float f32x4;

__device__ __forceinline__ u16 f2bf(float f) {
    union { float f; uint32_t u; } x; x.f = f;
    const uint32_t r = x.u + 0x7fffu + ((x.u >> 16) & 1u);
    return (u16)(r >> 16);
}
__device__ __forceinline__ float bf2f(u16 b) {
    union { uint32_t u; float f; } x; x.u = ((uint32_t)b) << 16;
    return x.f;
}

// Swizzled pointer into a 128-byte-row LDS tile: byte ^= (row&7)<<4.
__device__ __forceinline__ void* swzPtr(void* base, int row, int colByte) {
    return (char*)base + row * 128 + (colByte ^ ((row & 7) << 4));
}

// async global->LDS, 16B per lane; LDS dest is wave-uniform base + lane*16.
__device__ __forceinline__ void gl16(const u16* g, u16* l) {
    __builtin_amdgcn_global_load_lds(
        (const __attribute__((address_space(1))) void*)g,
        (__attribute__((address_space(3))) void*)l, 16, 0, 0);
}

// ---------------- K0: transpose-convert x[b][c][n] f32 -> xb[b][n][c] bf16 ----
__global__ __launch_bounds__(256) void transpose_kernel(
    const float* __restrict__ x, u16* __restrict__ xb)
{
    __shared__ u16 ts[64 * 64];
    const int t = threadIdx.x;
    const int b  = blockIdx.x & 3;
    const int cc = (blockIdx.x >> 2) & 7;
    const int nc = blockIdx.x >> 5;
    const int c0 = cc << 6, n0 = nc << 6;
    const float* xs = x + ((size_t)(b * C_IN + c0) << 12) + n0;
    for (int u = t; u < 1024; u += 256) {
        const int c = u >> 4, nq = (u & 15) << 2;
        const float4 v = *(const float4*)(xs + ((size_t)c << 12) + nq);
        ushort4 h;
        h.x = f2bf(v.x); h.y = f2bf(v.y); h.z = f2bf(v.z); h.w = f2bf(v.w);
        *(ushort4*)((char*)ts + c * 128 + ((nq << 1) ^ (((c >> 3) & 7) << 4))) = h;
    }
    __syncthreads();
    for (int u = t; u < 512; u += 256) {
        const int n = u >> 3, cg = u & 7;
        u16 pk[8];
        #pragma unroll
        for (int j = 0; j < 8; ++j) {
            const int c = (cg << 3) + j;
            pk[j] = *(const u16*)((char*)ts + c * 128 + ((n << 1) ^ (cg << 4)));
        }
        *(ushort4*)(xb + ((size_t)((b << 12) + n0 + n) << 9) + c0 + (cg << 3)) =
            *(ushort4*)&pk[0];
        *(ushort4*)(xb + ((size_t)((b << 12) + n0 + n) << 9) + c0 + (cg << 3) + 4) =
            *(ushort4*)&pk[4];
    }
}

// ---------------- K1: QKV projection, bf16 MFMA ----------------
// Q output is pre-scaled by log2e (attention softmax runs in exp2 domain).
__global__ __launch_bounds__(256) void qkv_kernel(
    const u16* __restrict__ xb,
    const float* __restrict__ Wq, const float* __restrict__ bq,
    const float* __restrict__ Wk, const float* __restrict__ bk,
    const float* __restrict__ Wv, const float* __restrict__ bv,
    u16* __restrict__ Qb, u16* __restrict__ Kb, u16* __restrict__ Vb)
{
    __shared__ u16 wt[64 * 64];   // W chunk  [o][64 c]
    __shared__ u16 xt[64 * 64];   // xb chunk [n][64 c]
    const int t = threadIdx.x;
    const int l = t & 63, w = t >> 6;
    const int lo = l & 15, hi = l >> 4;
    const int b  = blockIdx.x & 3;
    const int ot = (blockIdx.x >> 2) & 3;
    const int n0 = (blockIdx.x >> 4) << 6;
    const float* Wbase = (ot == 0) ? Wq : (ot == 1) ? Wk : (Wv + ((ot - 2) << 6) * C_IN);
    f32x4 acc[4];
    #pragma unroll
    for (int ti = 0; ti < 4; ++ti) acc[ti] = (f32x4){0.f, 0.f, 0.f, 0.f};

    for (int cc = 0; cc < 8; ++cc) {
        const int c0 = cc << 6;
        for (int u = t; u < 1024; u += 256) {      // W rows -> bf16
            const int i = u >> 4, c4 = (u & 15) << 2;
            const float4 v = *(const float4*)(Wbase + (size_t)i * C_IN + c0 + c4);
            ushort4 h;
            h.x = f2bf(v.x); h.y = f2bf(v.y); h.z = f2bf(v.z); h.w = f2bf(v.w);
            *(ushort4*)swzPtr(wt, i, c4 << 1) = h;
        }
        for (int u = t; u < 512; u += 256) {       // xb rows (already bf16)
            const int i = u >> 3, cb = (u & 7) << 4;
            *(uint4*)swzPtr(xt, i, cb) =
                *(const uint4*)(xb + ((size_t)((b << 12) + n0 + i) << 9) + c0 + (cb >> 1));
        }
        __syncthreads();
        if (ot < 2) {
            const bf16x8 af0 = *(const bf16x8*)swzPtr(xt, (w << 4) + lo, hi << 4);
            const bf16x8 af1 = *(const bf16x8*)swzPtr(xt, (w << 4) + lo, 64 + (hi << 4));
            #pragma unroll
            for (int ti = 0; ti < 4; ++ti) {
                const bf16x8 bf0 = *(const bf16x8*)swzPtr(wt, (ti << 4) + lo, hi << 4);
                const bf16x8 bf1 = *(const bf16x8*)swzPtr(wt, (ti << 4) + lo, 64 + (hi << 4));
                acc[ti] = __builtin_amdgcn_mfma_f32_16x16x32_bf16(af0, bf0, acc[ti], 0, 0, 0);
                acc[ti] = __builtin_amdgcn_mfma_f32_16x16x32_bf16(af1, bf1, acc[ti], 0, 0, 0);
            }
        } else {
            const bf16x8 af0 = *(const bf16x8*)swzPtr(wt, (w << 4) + lo, hi << 4);
            const bf16x8 af1 = *(const bf16x8*)swzPtr(wt, (w << 4) + lo, 64 + (hi << 4));
            #pragma unroll
            for (int ti = 0; ti < 4; ++ti) {
                const bf16x8 bf0 = *(const bf16x8*)swzPtr(xt, (ti << 4) + lo, hi << 4);
                const bf16x8 bf1 = *(const bf16x8*)swzPtr(xt, (ti << 4) + lo, 64 + (hi << 4));
                acc[ti] = __builtin_amdgcn_mfma_f32_16x16x32_bf16(af0, bf0, acc[ti], 0, 0, 0);
                acc[ti] = __builtin_amdgcn_mfma_f32_16x16x32_bf16(af1, bf1, acc[ti], 0, 0, 0);
            }
        }
        __syncthreads();
    }
    if (ot < 2) {   // D row = n_local, col = o_local -> [n][64ch]
        const float* bias_base = (ot == 0) ? bq : bk;
        u16* dst = (ot == 0) ? Qb : Kb;
        const float sc = (ot == 0) ? LOG2E : 1.0f;
        #pragma unroll
        for (int ti = 0; ti < 4; ++ti) {
            const float bias = bias_base[(ti << 4) + lo];
            #pragma unroll
            for (int r = 0; r < 4; ++r) {
                const int nrow = (w << 4) + (hi << 2) + r;
                dst[((size_t)((b << 12) + n0 + nrow) << 6) + (ti << 4) + lo] =
                    f2bf((acc[ti][r] + bias) * sc);
            }
        }
    } else {        // D row = cv_local, col = n_local -> [cv][n]
        #pragma unroll
        for (int r = 0; r < 4; ++r) {
            const int cv = ((ot - 2) << 6) + (w << 4) + (hi << 2) + r;
            const float bias = bv[cv];
            #pragma unroll
            for (int ti = 0; ti < 4; ++ti)
                Vb[((size_t)(b * C_V + cv) << 12) + n0 + (ti << 4) + lo] =
                    f2bf(acc[ti][r] + bias);
        }
    }
}

// ---------------- K2: MFMA flash attention ----------------
// Block: 128 queries (8 waves x 16 rows), KV split x4, 16 tiles of 64 keys.
// global_load_lds staging (pre-swizzled global source, linear LDS dest),
// K/V double-buffered, ONE barrier per tile. Softmax in exp2 domain with
// defer-max (THR=8); P packed via v_cvt_pk_bf16_f32.
__global__ __launch_bounds__(512, 4) void attn_kernel(
    const u16* __restrict__ Qb, const u16* __restrict__ Kb,
    const u16* __restrict__ Vb, u16* __restrict__ po,
    float* __restrict__ pm, float* __restrict__ pl)
{
    __shared__ u16 qs[128 * 64];      // 16 KB
    __shared__ u16 ks[2][64 * 64];    // 16 KB
    __shared__ u16 vs[2][128 * 64];   // 32 KB
    __shared__ u16 ps[128 * 64];      // 16 KB
    const int t = threadIdx.x;
    const int l = t & 63, w = t >> 6;          // 8 waves
    const int lo = l & 15, hi = l >> 4;
    const int b = blockIdx.x & 3;
    const int s = (blockIdx.x >> 2) & 3;
    const int n0 = (blockIdx.x >> 4) << 7;     // 128 q per block
    // pre-swizzled source column (u16 units): ((l&7) ^ (l>>3)) * 8
    const int colOff = ((l & 7) ^ (l >> 3)) << 3;
    const u16* kbase = Kb + ((size_t)b << 18);
    const u16* vbase = Vb + ((size_t)(b * C_V) << 12);
    const int m0base = s << 10;

    // ---- prologue: stage Q (16 KB) + K/V tile 0 via global_load_lds ----
    {
        const u16* qsrc = Qb + ((size_t)((b << 12) + n0) << 6);
        #pragma unroll
        for (int i = 0; i < 2; ++i) {
            const int r8 = (w << 4) + (i << 3);
            gl16(qsrc + ((size_t)(r8 + (l >> 3)) << 6) + colOff, &qs[r8 << 6]);
        }
    }
    gl16(kbase + ((size_t)(m0base + (w << 3) + (l >> 3)) << 6) + colOff,
         &ks[0][(w << 3) << 6]);
    #pragma unroll
    for (int i = 0; i < 2; ++i) {
        const int cv8 = (w << 4) + (i << 3);
        gl16(vbase + ((size_t)(cv8 + (l >> 3)) << 12) + m0base + colOff,
             &vs[0][cv8 << 6]);
    }
    float oldm[4] = {-1e30f, -1e30f, -1e30f, -1e30f};
    float lsum[4] = {0.f, 0.f, 0.f, 0.f};
    f32x4 oacc[8];
    #pragma unroll
    for (int tj = 0; tj < 8; ++tj) oacc[tj] = (f32x4){0.f, 0.f, 0.f, 0.f};
    asm volatile("s_waitcnt vmcnt(0)" ::: "memory");
    __syncthreads();

    const int qrow = (w << 4) + lo;
    const bf16x8 qf0 = *(const bf16x8*)swzPtr(qs, qrow, hi << 4);
    const bf16x8 qf1 = *(const bf16x8*)swzPtr(qs, qrow, 64 + (hi << 4));

    int cur = 0;
    for (int kt = 0; kt < 16; ++kt) {
        // prefetch next K/V tile into the other buffer (in flight across compute)
        if (kt < 15) {
            const int m1 = m0base + ((kt + 1) << 6);
            gl16(kbase + ((size_t)(m1 + (w << 3) + (l >> 3)) << 6) + colOff,
                 &ks[cur ^ 1][(w << 3) << 6]);
            #pragma unroll
            for (int i = 0; i < 2; ++i) {
                const int cv8 = (w << 4) + (i << 3);
                gl16(vbase + ((size_t)(cv8 + (l >> 3)) << 12) + m1 + colOff,
                     &vs[cur ^ 1][cv8 << 6]);
            }
        }
        // ---- S = Q·K^T (exp2 domain; Q pre-scaled by log2e) ----
        f32x4 sacc[4];
        #pragma unroll
        for (int ti = 0; ti < 4; ++ti) {
            const int krow = (ti << 4) + lo;
            const bf16x8 kb0 = *(const bf16x8*)swzPtr(ks[cur], krow, hi << 4);
            const bf16x8 kb1 = *(const bf16x8*)swzPtr(ks[cur], krow, 64 + (hi << 4));
            f32x4 z = (f32x4){0.f, 0.f, 0.f, 0.f};
            z = __builtin_amdgcn_mfma_f32_16x16x32_bf16(qf0, kb0, z, 0, 0, 0);
            sacc[ti] = __builtin_amdgcn_mfma_f32_16x16x32_bf16(qf1, kb1, z, 0, 0, 0);
        }
        // ---- online softmax with defer-max ----
        float al[4];
        bool need = false;
        #pragma unroll
        for (int r = 0; r < 4; ++r) {
            float m = fmaxf(fmaxf(sacc[0][r], sacc[1][r]), fmaxf(sacc[2][r], sacc[3][r]));
            m = fmaxf(m, __shfl_xor(m, 1));
            m = fmaxf(m, __shfl_xor(m, 2));
            m = fmaxf(m, __shfl_xor(m, 4));
            m = fmaxf(m, __shfl_xor(m, 8));
            if (__all(m <= oldm[r] + 8.0f)) {
                al[r] = 1.0f;
            } else {
                const float nm = fmaxf(oldm[r], m);
                al[r] = exp2f(oldm[r] - nm);
                oldm[r] = nm;
                need = true;
            }
        }
        if (need) {
            #pragma unroll
            for (int tj = 0; tj < 8; ++tj)
                #pragma unroll
                for (int r = 0; r < 4; ++r) oacc[tj][r] *= al[r];
            #pragma unroll
            for (int r = 0; r < 4; ++r) lsum[r] *= al[r];
        }
        #pragma unroll
        for (int r = 0; r < 4; ++r) {
            const int prow = (w << 4) + (hi << 2) + r;
            const float p0 = exp2f(sacc[0][r] - oldm[r]);
            const float p1 = exp2f(sacc[1][r] - oldm[r]);
            const float p2 = exp2f(sacc[2][r] - oldm[r]);
            const float p3 = exp2f(sacc[3][r] - oldm[r]);
            uint32_t u01, u23;
            asm("v_cvt_pk_bf16_f32 %0, %1, %2" : "=v"(u01) : "v"(p0), "v"(p1));
            asm("v_cvt_pk_bf16_f32 %0, %1, %2" : "=v"(u23) : "v"(p2), "v"(p3));
            *(u16*)swzPtr(ps, prow, lo << 1)           = (u16)u01;
            *(u16*)swzPtr(ps, prow, (16 + lo) << 1)    = (u16)(u01 >> 16);
            *(u16*)swzPtr(ps, prow, (32 + lo) << 1)    = (u16)u23;
            *(u16*)swzPtr(ps, prow, (48 + lo) << 1)    = (u16)(u23 >> 16);
            float pp = (p0 + p1) + (p2 + p3);
            pp += __shfl_xor(pp, 1);
            pp += __shfl_xor(pp, 2);
            pp += __shfl_xor(pp, 4);
            pp += __shfl_xor(pp, 8);
            lsum[r] += pp;
        }
        // own-wave P rows; order write->read (rule 18)
        asm volatile("s_waitcnt lgkmcnt(0)" ::: "memory");
        __builtin_amdgcn_sched_barrier(0);

        // ---- O += P·V ----
        const bf16x8 pa0 = *(const bf16x8*)swzPtr(ps, qrow, hi << 4);
        const bf16x8 pa1 = *(const bf16x8*)swzPtr(ps, qrow, 64 + (hi << 4));
        #pragma unroll
        for (int tj = 0; tj < 8; ++tj) {
            const int vrow = (tj << 4) + lo;
            const bf16x8 vb0 = *(const bf16x8*)swzPtr(vs[cur], vrow, hi << 4);
            const bf16x8 vb1 = *(const bf16x8*)swzPtr(vs[cur], vrow, 64 + (hi << 4));
            oacc[tj] = __builtin_amdgcn_mfma_f32_16x16x32_bf16(pa0, vb0, oacc[tj], 0, 0, 0);
            oacc[tj] = __builtin_amdgcn_mfma_f32_16x16x32_bf16(pa1, vb1, oacc[tj], 0, 0, 0);
        }
        // next-tile loads landed + everyone done reading cur before overwrite
        asm volatile("s_waitcnt vmcnt(0)" ::: "memory");
        __syncthreads();
        cur ^= 1;
    }
    // ---- partial epilogue: unnormalized O (bf16) + stats ----
    u16* pod = po + ((size_t)blockIdx.x << 14);
    #pragma unroll
    for (int tj = 0; tj < 8; ++tj)
        #pragma unroll
        for (int r = 0; r < 4; ++r) {
            const int q = (w << 4) + (hi << 2) + r;
            pod[(q << 7) + (tj << 4) + lo] = f2bf(oacc[tj][r]);
        }
    if (lo == 0) {
        #pragma unroll
        for (int r = 0; r < 4; ++r) {
            const int q = (w << 4) + (hi << 2) + r;
            pm[(blockIdx.x << 7) + q] = oldm[r];
            pl[(blockIdx.x << 7) + q] = lsum[r];
        }
    }
}

// ---------------- K2b: flash combine (4 splits) -> Ob[b][n][cv] bf16 ----------
__global__ __launch_bounds__(256) void combine_kernel(
    const u16* __restrict__ po, const float* __restrict__ pm,
    const float* __restrict__ pl, u16* __restrict__ Ob)
{
    __shared__ float fs[4][64];
    __shared__ float invl[64];
    const int t = threadIdx.x;
    const int b = blockIdx.x & 3;
    const int qc = blockIdx.x >> 2;       // 64-q chunk, 0..63
    const int n0 = qc << 6;
    const int qc7 = qc >> 1;              // owning 128-q attn block row
    const int qoff = (qc & 1) << 6;
    int slot[4];
    #pragma unroll
    for (int s = 0; s < 4; ++s) slot[s] = b + (s << 2) + (qc7 << 4);
    if (t < 64) {
        const float m0 = pm[(slot[0] << 7) + qoff + t];
        const float m1 = pm[(slot[1] << 7) + qoff + t];
        const float m2 = pm[(slot[2] << 7) + qoff + t];
        const float m3 = pm[(slot[3] << 7) + qoff + t];
        const float mg = fmaxf(fmaxf(m0, m1), fmaxf(m2, m3));
        const float f0 = exp2f(m0 - mg), f1 = exp2f(m1 - mg);
        const float f2 = exp2f(m2 - mg), f3 = exp2f(m3 - mg);
        const float lg = pl[(slot[0] << 7) + qoff + t] * f0 +
                         pl[(slot[1] << 7) + qoff + t] * f1 +
                         pl[(slot[2] << 7) + qoff + t] * f2 +
                         pl[(slot[3] << 7) + qoff + t] * f3;
        fs[0][t] = f0; fs[1][t] = f1; fs[2][t] = f2; fs[3][t] = f3;
        invl[t] = 1.0f / lg;
    }
    __syncthreads();
    for (int u = t; u < 2048; u += 256) {
        const int q = u >> 5, c4 = (u & 31) << 2;
        float a0 = 0.f, a1 = 0.f, a2 = 0.f, a3 = 0.f;
        #pragma unroll
        for (int s = 0; s < 4; ++s) {
            const ushort4 h = *(const ushort4*)(po + ((size_t)slot[s] << 14) +
                                                ((qoff + q) << 7) + c4);
            const float f = fs[s][q];
            a0 += bf2f(h.x) * f; a1 += bf2f(h.y) * f;
            a2 += bf2f(h.z) * f; a3 += bf2f(h.w) * f;
        }
        const float il = invl[q];
        ushort4 o;
        o.x = f2bf(a0 * il); o.y = f2bf(a1 * il);
        o.z = f2bf(a2 * il); o.w = f2bf(a3 * il);
        *(ushort4*)(Ob + ((size_t)((b << 12) + n0 + q) << 7) + c4) = o;
    }
}

// ---------------- K3: output projection + residual, bf16 MFMA ----------------
__global__ __launch_bounds__(256) void proj_kernel(
    const u16* __restrict__ Ob, const float* __restrict__ Wo,
    const float* __restrict__ bo, const float* __restrict__ x,
    const float* __restrict__ gamma_p, float* __restrict__ out)
{
    __shared__ union {
        struct { u16 wl0[64 * 64]; u16 wl1[64 * 64]; u16 ob0[64 * 64]; u16 ob1[64 * 64]; } s;
        float tr[64 * 64];
    } sm;
    const int t = threadIdx.x;
    const int l = t & 63, w = t >> 6;
    const int lo = l & 15, hi = l >> 4;
    const int b  = blockIdx.x & 3;
    const int co0 = ((blockIdx.x >> 2) & 7) << 6;
    const int n0  = (blockIdx.x >> 5) << 6;
    for (int u = t; u < 2048; u += 256) {
        const int i = u >> 5, c4 = (u & 31) << 2;
        const float4 v = *(const float4*)(Wo + (size_t)(co0 + i) * C_V + c4);
        ushort4 h;
        h.x = f2bf(v.x); h.y = f2bf(v.y); h.z = f2bf(v.z); h.w = f2bf(v.w);
        *(ushort4*)swzPtr((c4 < 64) ? sm.s.wl0 : sm.s.wl1, i, (c4 & 63) << 1) = h;
    }
    for (int u = t; u < 1024; u += 256) {
        const int i = u >> 4, cb = (u & 15) << 4;
        *(uint4*)swzPtr((cb < 128) ? sm.s.ob0 : sm.s.ob1, i, cb & 127) =
            *(const uint4*)(Ob + ((size_t)((b << 12) + n0 + i) << 7) + (cb >> 1));
    }
    __syncthreads();
    const int arow = (w << 4) + lo;
    const bf16x8 af00 = *(const bf16x8*)swzPtr(sm.s.wl0, arow, hi << 4);
    const bf16x8 af01 = *(const bf16x8*)swzPtr(sm.s.wl0, arow, 64 + (hi << 4));
    const bf16x8 af10 = *(const bf16x8*)swzPtr(sm.s.wl1, arow, hi << 4);
    const bf16x8 af11 = *(const bf16x8*)swzPtr(sm.s.wl1, arow, 64 + (hi << 4));
    f32x4 acc[4];
    #pragma unroll
    for (int ti = 0; ti < 4; ++ti) {
        const int brow = (ti << 4) + lo;
        f32x4 z = (f32x4){0.f, 0.f, 0.f, 0.f};
        z = __builtin_amdgcn_mfma_f32_16x16x32_bf16(af00, *(const bf16x8*)swzPtr(sm.s.ob0, brow, hi << 4), z, 0, 0, 0);
        z = __builtin_amdgcn_mfma_f32_16x16x32_bf16(af01, *(const bf16x8*)swzPtr(sm.s.ob0, brow, 64 + (hi << 4)), z, 0, 0, 0);
        z = __builtin_amdgcn_mfma_f32_16x16x32_bf16(af10, *(const bf16x8*)swzPtr(sm.s.ob1, brow, hi << 4), z, 0, 0, 0);
        acc[ti] = __builtin_amdgcn_mfma_f32_16x16x32_bf16(af11, *(const bf16x8*)swzPtr(sm.s.ob1, brow, 64 + (hi << 4)), z, 0, 0, 0);
    }
    __syncthreads();
    #pragma unroll
    for (int ti = 0; ti < 4; ++ti)
        #pragma unroll
        for (int r = 0; r < 4; ++r) {
            const int co = (w << 4) + (hi << 2) + r;
            const int n  = (ti << 4) + lo;
            sm.tr[(co << 6) + (n ^ (((co >> 2) & 3) << 2))] = acc[ti][r];
        }
    __syncthreads();
    const float g = gamma_p[0];
    for (int u = t; u < 1024; u += 256) {
        const int co = u >> 4, n4 = (u & 15) << 2;
        const float4 av = *(const float4*)&sm.tr[(co << 6) + (n4 ^ (((co >> 2) & 3) << 2))];
        const int o = co0 + co;
        const size_t off = ((size_t)(b * C_IN + o) << 12) + n0 + n4;
        const float4 xv = *(const float4*)(x + off);
        const float bias = bo[o];
        float4 rs;
        rs.x = xv.x + g * (av.x + bias);
        rs.y = xv.y + g * (av.y + bias);
        rs.z = xv.z + g * (av.z + bias);
        rs.w = xv.w + g * (av.w + bias);
        *(float4*)(out + off) = rs;
    }
}

extern "C" void kernel_launch(void* const* d_in, const int* in_sizes, int n_in,
                              void* d_out, int out_size, void* d_ws, size_t ws_size,
                              hipStream_t stream) {
    (void)in_sizes; (void)n_in; (void)out_size; (void)ws_size;
    const float* x  = (const float*)d_in[0];
    const float* Wq = (const float*)d_in[1];
    const float* bq = (const float*)d_in[2];
    const float* Wk = (const float*)d_in[3];
    const float* bk = (const float*)d_in[4];
    const float* Wv = (const float*)d_in[5];
    const float* bv = (const float*)d_in[6];
    const float* Wo = (const float*)d_in[7];
    const float* bo = (const float*)d_in[8];
    const float* gm = (const float*)d_in[9];
    float* out = (float*)d_out;
    // ws layout (bytes): [0,16M): xb bf16 (K0->K1) ALIASED with po bf16 (K2->K2b)
    //   then Qb 2M | Kb 2M | Vb 4M | pm 256K | pl 256K | Ob 4M   (~28.5 MB total)
    u16* xb = (u16*)d_ws;
    u16* po = (u16*)d_ws;                        // alias: xb dead after K1
    u16* Qb = xb + (size_t)8 * 1024 * 1024;
    u16* Kb = Qb + (size_t)4 * N_SP * C_QK;
    u16* Vb = Kb + (size_t)4 * N_SP * C_QK;
    float* pm = (float*)(Vb + (size_t)4 * C_V * N_SP);
    float* pl = pm + 512 * 128;
    u16* Ob = (u16*)(pl + 512 * 128);
    transpose_kernel<<<2048, 256, 0, stream>>>(x, xb);
    qkv_kernel<<<1024, 256, 0, stream>>>(xb, Wq, bq, Wk, bk, Wv, bv, Qb, Kb, Vb);
    attn_kernel<<<512, 512, 0, stream>>>(Qb, Kb, Vb, po, pm, pl);
    combine_kernel<<<256, 256, 0, stream>>>(po, pm, pl, Ob);
    proj_kernel<<<2048, 256, 0, stream>>>(Ob, Wo, bo, x, gm, out);
}

// Round 5
// 113.593 us; speedup vs baseline: 8.1922x; 1.1142x over previous
//
#include <hip/hip_runtime.h>
#include <cstdint>
#include <cstddef>

#define N_SP 4096
#define C_IN 512
#define C_QK 64
#define C_V  128
#define LOG2E 1.4426950408889634f

typedef unsigned short u16;
typedef __attribute__((ext_vector_type(8))) short bf16x8;
typedef __attribute__((ext_vector_type(4))) float f32x4;
typedef __attribute__((ext_vector_type(16))) float f32x16;

__device__ __forceinline__ u16 f2bf(float f) {
    union { float f; uint32_t u; } x; x.f = f;
    const uint32_t r = x.u + 0x7fffu + ((x.u >> 16) & 1u);
    return (u16)(r >> 16);
}
__device__ __forceinline__ float bf2f(u16 b) {
    union { uint32_t u; float f; } x; x.u = ((uint32_t)b) << 16;
    return x.f;
}

// Swizzled pointer into a 128-byte-row LDS tile: byte ^= (row&7)<<4.
__device__ __forceinline__ void* swzPtr(void* base, int row, int colByte) {
    return (char*)base + row * 128 + (colByte ^ ((row & 7) << 4));
}

// async global->LDS, 16B per lane; LDS dest is wave-uniform base + lane*16.
__device__ __forceinline__ void gl16(const u16* g, u16* l) {
    __builtin_amdgcn_global_load_lds(
        (const __attribute__((address_space(1))) void*)g,
        (__attribute__((address_space(3))) void*)l, 16, 0, 0);
}

// ---------------- K0: transpose-convert x[b][c][n] f32 -> xb[b][n][c] bf16 ----
__global__ __launch_bounds__(256) void transpose_kernel(
    const float* __restrict__ x, u16* __restrict__ xb)
{
    __shared__ u16 ts[64 * 64];
    const int t = threadIdx.x;
    const int b  = blockIdx.x & 3;
    const int cc = (blockIdx.x >> 2) & 7;
    const int nc = blockIdx.x >> 5;
    const int c0 = cc << 6, n0 = nc << 6;
    const float* xs = x + ((size_t)(b * C_IN + c0) << 12) + n0;
    for (int u = t; u < 1024; u += 256) {
        const int c = u >> 4, nq = (u & 15) << 2;
        const float4 v = *(const float4*)(xs + ((size_t)c << 12) + nq);
        ushort4 h;
        h.x = f2bf(v.x); h.y = f2bf(v.y); h.z = f2bf(v.z); h.w = f2bf(v.w);
        *(ushort4*)((char*)ts + c * 128 + ((nq << 1) ^ (((c >> 3) & 7) << 4))) = h;
    }
    __syncthreads();
    for (int u = t; u < 512; u += 256) {
        const int n = u >> 3, cg = u & 7;
        u16 pk[8];
        #pragma unroll
        for (int j = 0; j < 8; ++j) {
            const int c = (cg << 3) + j;
            pk[j] = *(const u16*)((char*)ts + c * 128 + ((n << 1) ^ (cg << 4)));
        }
        *(ushort4*)(xb + ((size_t)((b << 12) + n0 + n) << 9) + c0 + (cg << 3)) =
            *(ushort4*)&pk[0];
        *(ushort4*)(xb + ((size_t)((b << 12) + n0 + n) << 9) + c0 + (cg << 3) + 4) =
            *(ushort4*)&pk[4];
    }
}

// ---------------- K1: QKV projection, bf16 MFMA ----------------
// Q output is pre-scaled by log2e (attention softmax runs in exp2 domain).
__global__ __launch_bounds__(256) void qkv_kernel(
    const u16* __restrict__ xb,
    const float* __restrict__ Wq, const float* __restrict__ bq,
    const float* __restrict__ Wk, const float* __restrict__ bk,
    const float* __restrict__ Wv, const float* __restrict__ bv,
    u16* __restrict__ Qb, u16* __restrict__ Kb, u16* __restrict__ Vb)
{
    __shared__ u16 wt[64 * 64];   // W chunk  [o][64 c]
    __shared__ u16 xt[64 * 64];   // xb chunk [n][64 c]
    const int t = threadIdx.x;
    const int l = t & 63, w = t >> 6;
    const int lo = l & 15, hi = l >> 4;
    const int b  = blockIdx.x & 3;
    const int ot = (blockIdx.x >> 2) & 3;
    const int n0 = (blockIdx.x >> 4) << 6;
    const float* Wbase = (ot == 0) ? Wq : (ot == 1) ? Wk : (Wv + ((ot - 2) << 6) * C_IN);
    f32x4 acc[4];
    #pragma unroll
    for (int ti = 0; ti < 4; ++ti) acc[ti] = (f32x4){0.f, 0.f, 0.f, 0.f};

    for (int cc = 0; cc < 8; ++cc) {
        const int c0 = cc << 6;
        for (int u = t; u < 1024; u += 256) {      // W rows -> bf16
            const int i = u >> 4, c4 = (u & 15) << 2;
            const float4 v = *(const float4*)(Wbase + (size_t)i * C_IN + c0 + c4);
            ushort4 h;
            h.x = f2bf(v.x); h.y = f2bf(v.y); h.z = f2bf(v.z); h.w = f2bf(v.w);
            *(ushort4*)swzPtr(wt, i, c4 << 1) = h;
        }
        for (int u = t; u < 512; u += 256) {       // xb rows (already bf16)
            const int i = u >> 3, cb = (u & 7) << 4;
            *(uint4*)swzPtr(xt, i, cb) =
                *(const uint4*)(xb + ((size_t)((b << 12) + n0 + i) << 9) + c0 + (cb >> 1));
        }
        __syncthreads();
        if (ot < 2) {
            const bf16x8 af0 = *(const bf16x8*)swzPtr(xt, (w << 4) + lo, hi << 4);
            const bf16x8 af1 = *(const bf16x8*)swzPtr(xt, (w << 4) + lo, 64 + (hi << 4));
            #pragma unroll
            for (int ti = 0; ti < 4; ++ti) {
                const bf16x8 bf0 = *(const bf16x8*)swzPtr(wt, (ti << 4) + lo, hi << 4);
                const bf16x8 bf1 = *(const bf16x8*)swzPtr(wt, (ti << 4) + lo, 64 + (hi << 4));
                acc[ti] = __builtin_amdgcn_mfma_f32_16x16x32_bf16(af0, bf0, acc[ti], 0, 0, 0);
                acc[ti] = __builtin_amdgcn_mfma_f32_16x16x32_bf16(af1, bf1, acc[ti], 0, 0, 0);
            }
        } else {
            const bf16x8 af0 = *(const bf16x8*)swzPtr(wt, (w << 4) + lo, hi << 4);
            const bf16x8 af1 = *(const bf16x8*)swzPtr(wt, (w << 4) + lo, 64 + (hi << 4));
            #pragma unroll
            for (int ti = 0; ti < 4; ++ti) {
                const bf16x8 bf0 = *(const bf16x8*)swzPtr(xt, (ti << 4) + lo, hi << 4);
                const bf16x8 bf1 = *(const bf16x8*)swzPtr(xt, (ti << 4) + lo, 64 + (hi << 4));
                acc[ti] = __builtin_amdgcn_mfma_f32_16x16x32_bf16(af0, bf0, acc[ti], 0, 0, 0);
                acc[ti] = __builtin_amdgcn_mfma_f32_16x16x32_bf16(af1, bf1, acc[ti], 0, 0, 0);
            }
        }
        __syncthreads();
    }
    if (ot < 2) {   // D row = n_local, col = o_local -> [n][64ch]
        const float* bias_base = (ot == 0) ? bq : bk;
        u16* dst = (ot == 0) ? Qb : Kb;
        const float sc = (ot == 0) ? LOG2E : 1.0f;
        #pragma unroll
        for (int ti = 0; ti < 4; ++ti) {
            const float bias = bias_base[(ti << 4) + lo];
            #pragma unroll
            for (int r = 0; r < 4; ++r) {
                const int nrow = (w << 4) + (hi << 2) + r;
                dst[((size_t)((b << 12) + n0 + nrow) << 6) + (ti << 4) + lo] =
                    f2bf((acc[ti][r] + bias) * sc);
            }
        }
    } else {        // D row = cv_local, col = n_local -> [cv][n]
        #pragma unroll
        for (int r = 0; r < 4; ++r) {
            const int cv = ((ot - 2) << 6) + (w << 4) + (hi << 2) + r;
            const float bias = bv[cv];
            #pragma unroll
            for (int ti = 0; ti < 4; ++ti)
                Vb[((size_t)(b * C_V + cv) << 12) + n0 + (ti << 4) + lo] =
                    f2bf(acc[ti][r] + bias);
        }
    }
}

// ---------------- K2: MFMA flash attention, swapped 32x32 ----------------
// Block: 128 queries (4 waves x 32), KV split x4, 16 tiles of 64 keys.
// S^T = mfma32(K,Q): lane owns query col=lane&31; key=(r&3)+8*(r>>2)+4*(l>>5).
// Softmax fully in-register (in-lane tree + shfl_xor(32)); P^T rebuilt as the
// PV B-operand via cvt_pk + shfl_xor(32) exchange (no P LDS round-trip).
// O^T = mfma32(V,P^T) -> po[cv][q] partials (unnormalized) + m,l stats.
__global__ __launch_bounds__(256, 2) void attn_kernel(
    const u16* __restrict__ Qb, const u16* __restrict__ Kb,
    const u16* __restrict__ Vb, u16* __restrict__ po,
    float* __restrict__ pm, float* __restrict__ pl)
{
    __shared__ u16 ksm[2][64 * 64];    // 16 KB [key][64ch]
    __shared__ u16 vsm[2][128 * 64];   // 32 KB [cv][64key]
    const int t = threadIdx.x;
    const int l = t & 63, w = t >> 6;          // 4 waves
    const int l31 = l & 31, h = l >> 5;
    const int b = blockIdx.x & 3;
    const int s = (blockIdx.x >> 2) & 3;
    const int qc = blockIdx.x >> 4;
    const int n0 = qc << 7;                    // 128 q per block
    const int colOff = ((l & 7) ^ (l >> 3)) << 3;   // pre-swizzled source col
    const u16* kbase = Kb + ((size_t)b << 18);
    const u16* vbase = Vb + ((size_t)(b * C_V) << 12);
    const int m0base = s << 10;

    // Q B-frags straight from global (row = this lane's query)
    const u16* qrow_p = Qb + ((size_t)((b << 12) + n0 + (w << 5) + l31) << 6) + (h << 3);
    bf16x8 qf[4];
    #pragma unroll
    for (int ks = 0; ks < 4; ++ks) qf[ks] = *(const bf16x8*)(qrow_p + (ks << 4));

    // stage K/V tile 0
    #pragma unroll
    for (int i = 0; i < 2; ++i) {
        const int kr = (w << 4) + (i << 3);
        gl16(kbase + ((size_t)(m0base + kr + (l >> 3)) << 6) + colOff, &ksm[0][kr << 6]);
    }
    #pragma unroll
    for (int i = 0; i < 4; ++i) {
        const int cv = (w << 5) + (i << 3);
        gl16(vbase + ((size_t)(cv + (l >> 3)) << 12) + m0base + colOff, &vsm[0][cv << 6]);
    }
    float m_run = -1e30f, lsum = 0.f;
    f32x16 oacc[4];
    #pragma unroll
    for (int tj = 0; tj < 4; ++tj)
        #pragma unroll
        for (int i = 0; i < 16; ++i) oacc[tj][i] = 0.f;
    asm volatile("s_waitcnt vmcnt(0)" ::: "memory");
    __syncthreads();

    int cur = 0;
    for (int kt = 0; kt < 16; ++kt) {
        if (kt < 15) {   // prefetch next tile into other buffer
            const int m1 = m0base + ((kt + 1) << 6);
            #pragma unroll
            for (int i = 0; i < 2; ++i) {
                const int kr = (w << 4) + (i << 3);
                gl16(kbase + ((size_t)(m1 + kr + (l >> 3)) << 6) + colOff,
                     &ksm[cur ^ 1][kr << 6]);
            }
            #pragma unroll
            for (int i = 0; i < 4; ++i) {
                const int cv = (w << 5) + (i << 3);
                gl16(vbase + ((size_t)(cv + (l >> 3)) << 12) + m1 + colOff,
                     &vsm[cur ^ 1][cv << 6]);
            }
        }
        // ---- S^T = K·Q : two 32-key tiles x 4 k-steps ----
        f32x16 sa0, sa1;
        #pragma unroll
        for (int i = 0; i < 16; ++i) { sa0[i] = 0.f; sa1[i] = 0.f; }
        #pragma unroll
        for (int ks = 0; ks < 4; ++ks) {
            const bf16x8 k0 = *(const bf16x8*)swzPtr(ksm[cur], l31,      (h << 4) + (ks << 5));
            const bf16x8 k1 = *(const bf16x8*)swzPtr(ksm[cur], 32 + l31, (h << 4) + (ks << 5));
            sa0 = __builtin_amdgcn_mfma_f32_32x32x16_bf16(k0, qf[ks], sa0, 0, 0, 0);
            sa1 = __builtin_amdgcn_mfma_f32_32x32x16_bf16(k1, qf[ks], sa1, 0, 0, 0);
        }
        // ---- softmax, all in registers (exp2 domain) ----
        float mx[8];
        #pragma unroll
        for (int i = 0; i < 8; ++i)
            mx[i] = fmaxf(fmaxf(sa0[i], sa0[i + 8]), fmaxf(sa1[i], sa1[i + 8]));
        #pragma unroll
        for (int i = 0; i < 4; ++i) mx[i] = fmaxf(mx[i], mx[i + 4]);
        mx[0] = fmaxf(fmaxf(mx[0], mx[1]), fmaxf(mx[2], mx[3]));
        const float pmax = fmaxf(mx[0], __shfl_xor(mx[0], 32));
        if (!__all(pmax <= m_run + 8.0f)) {     // defer-max (THR=8)
            const float nm = fmaxf(m_run, pmax);
            const float al = exp2f(m_run - nm);
            m_run = nm;
            #pragma unroll
            for (int tj = 0; tj < 4; ++tj)
                #pragma unroll
                for (int i = 0; i < 16; ++i) oacc[tj][i] *= al;
            lsum *= al;
        }
        float p0[16], p1[16];
        #pragma unroll
        for (int i = 0; i < 16; ++i) {
            p0[i] = exp2f(sa0[i] - m_run);
            p1[i] = exp2f(sa1[i] - m_run);
        }
        float sm8[8];
        #pragma unroll
        for (int i = 0; i < 8; ++i) sm8[i] = (p0[i] + p0[i + 8]) + (p1[i] + p1[i + 8]);
        #pragma unroll
        for (int i = 0; i < 4; ++i) sm8[i] += sm8[i + 4];
        float ps = (sm8[0] + sm8[1]) + (sm8[2] + sm8[3]);
        ps += __shfl_xor(ps, 32);
        lsum += ps;
        // ---- pack P -> bf16 pairs: P2[kt2][g][pr] = pk(p[4g+2pr], p[4g+2pr+1]) ----
        uint32_t P2[2][4][2];
        #pragma unroll
        for (int g = 0; g < 4; ++g)
            #pragma unroll
            for (int pr = 0; pr < 2; ++pr) {
                asm("v_cvt_pk_bf16_f32 %0, %1, %2"
                    : "=v"(P2[0][g][pr]) : "v"(p0[4 * g + 2 * pr]), "v"(p0[4 * g + 2 * pr + 1]));
                asm("v_cvt_pk_bf16_f32 %0, %1, %2"
                    : "=v"(P2[1][g][pr]) : "v"(p1[4 * g + 2 * pr]), "v"(p1[4 * g + 2 * pr + 1]));
            }
        // ---- assemble P^T B-frags via shfl_xor(32) exchange ----
        bf16x8 pf[4];
        #pragma unroll
        for (int ks = 0; ks < 4; ++ks) {
            const int iE = ks << 1, iO = iE + 1;
            uint32_t fr[4];
            #pragma unroll
            for (int pr = 0; pr < 2; ++pr) {
                const uint32_t X = P2[iE >> 2][iE & 3][pr];
                const uint32_t Y = P2[iO >> 2][iO & 3][pr];
                const uint32_t Xs = (uint32_t)__shfl_xor((int)X, 32);
                const uint32_t Ys = (uint32_t)__shfl_xor((int)Y, 32);
                fr[pr]     = h ? Ys : X;
                fr[2 + pr] = h ? Y  : Xs;
            }
            pf[ks] = *(bf16x8*)fr;
        }
        // ---- O^T += V·P^T : 4 cv-tiles x 4 k-steps ----
        #pragma unroll
        for (int tj = 0; tj < 4; ++tj)
            #pragma unroll
            for (int ks = 0; ks < 4; ++ks) {
                const bf16x8 vf =
                    *(const bf16x8*)swzPtr(vsm[cur], (tj << 5) + l31, (h << 4) + (ks << 5));
                oacc[tj] = __builtin_amdgcn_mfma_f32_32x32x16_bf16(vf, pf[ks], oacc[tj], 0, 0, 0);
            }
        asm volatile("s_waitcnt vmcnt(0)" ::: "memory");
        __syncthreads();
        cur ^= 1;
    }
    // ---- epilogue: unnormalized O^T partials (bf16) + stats ----
    u16* pod = po + ((size_t)blockIdx.x << 14);   // [128 cv][128 q]
    #pragma unroll
    for (int tj = 0; tj < 4; ++tj)
        #pragma unroll
        for (int r = 0; r < 16; ++r) {
            const int cv = (tj << 5) + (r & 3) + ((r >> 2) << 3) + (h << 2);
            pod[(cv << 7) + (w << 5) + l31] = f2bf(oacc[tj][r]);
        }
    if (h == 0) {
        pm[(blockIdx.x << 7) + (w << 5) + l31] = m_run;
        pl[(blockIdx.x << 7) + (w << 5) + l31] = lsum;
    }
}

// ---------------- K2b: flash combine (4 splits) -> Ob[b][n][cv] bf16 ----------
// po partials are [cv][q]-major; transpose to [n][cv] through LDS.
__global__ __launch_bounds__(256) void combine_kernel(
    const u16* __restrict__ po, const float* __restrict__ pm,
    const float* __restrict__ pl, u16* __restrict__ Ob)
{
    __shared__ float fs[4][128];
    __shared__ float invl[128];
    __shared__ float tr[64][132];
    const int t = threadIdx.x;
    const int b = blockIdx.x & 3;
    const int qc = blockIdx.x >> 2;            // 0..31 (128-q chunks)
    int slot[4];
    #pragma unroll
    for (int s = 0; s < 4; ++s) slot[s] = b + (s << 2) + (qc << 4);
    if (t < 128) {
        const float m0 = pm[(slot[0] << 7) + t], m1 = pm[(slot[1] << 7) + t];
        const float m2 = pm[(slot[2] << 7) + t], m3 = pm[(slot[3] << 7) + t];
        const float mg = fmaxf(fmaxf(m0, m1), fmaxf(m2, m3));
        const float f0 = exp2f(m0 - mg), f1 = exp2f(m1 - mg);
        const float f2 = exp2f(m2 - mg), f3 = exp2f(m3 - mg);
        const float lg = pl[(slot[0] << 7) + t] * f0 + pl[(slot[1] << 7) + t] * f1 +
                         pl[(slot[2] << 7) + t] * f2 + pl[(slot[3] << 7) + t] * f3;
        fs[0][t] = f0; fs[1][t] = f1; fs[2][t] = f2; fs[3][t] = f3;
        invl[t] = 1.0f / lg;
    }
    __syncthreads();
    #pragma unroll
    for (int qh = 0; qh < 2; ++qh) {
        for (int u = t; u < 2048; u += 256) {           // accumulate -> LDS [q][cv]
            const int cv = u >> 4, q4 = (u & 15) << 2;
            const int q = (qh << 6) + q4;
            float a0 = 0.f, a1 = 0.f, a2 = 0.f, a3 = 0.f;
            #pragma unroll
            for (int s = 0; s < 4; ++s) {
                const ushort4 hv =
                    *(const ushort4*)(po + ((size_t)slot[s] << 14) + (cv << 7) + q);
                a0 += bf2f(hv.x) * fs[s][q];
                a1 += bf2f(hv.y) * fs[s][q + 1];
                a2 += bf2f(hv.z) * fs[s][q + 2];
                a3 += bf2f(hv.w) * fs[s][q + 3];
            }
            tr[q4 + 0][cv] = a0 * invl[q];
            tr[q4 + 1][cv] = a1 * invl[q + 1];
            tr[q4 + 2][cv] = a2 * invl[q + 2];
            tr[q4 + 3][cv] = a3 * invl[q + 3];
        }
        __syncthreads();
        for (int u = t; u < 2048; u += 256) {           // write [n][cv]
            const int q = u >> 5, c4 = (u & 31) << 2;
            const float4 v = *(const float4*)&tr[q][c4];
            ushort4 o;
            o.x = f2bf(v.x); o.y = f2bf(v.y); o.z = f2bf(v.z); o.w = f2bf(v.w);
            const int n = (qc << 7) + (qh << 6) + q;
            *(ushort4*)(Ob + ((size_t)((b << 12) + n) << 7) + c4) = o;
        }
        __syncthreads();
    }
}

// ---------------- K3: output projection + residual, bf16 MFMA ----------------
__global__ __launch_bounds__(256) void proj_kernel(
    const u16* __restrict__ Ob, const float* __restrict__ Wo,
    const float* __restrict__ bo, const float* __restrict__ x,
    const float* __restrict__ gamma_p, float* __restrict__ out)
{
    __shared__ union {
        struct { u16 wl0[64 * 64]; u16 wl1[64 * 64]; u16 ob0[64 * 64]; u16 ob1[64 * 64]; } s;
        float tr[64 * 64];
    } sm;
    const int t = threadIdx.x;
    const int l = t & 63, w = t >> 6;
    const int lo = l & 15, hi = l >> 4;
    const int b  = blockIdx.x & 3;
    const int co0 = ((blockIdx.x >> 2) & 7) << 6;
    const int n0  = (blockIdx.x >> 5) << 6;
    for (int u = t; u < 2048; u += 256) {
        const int i = u >> 5, c4 = (u & 31) << 2;
        const float4 v = *(const float4*)(Wo + (size_t)(co0 + i) * C_V + c4);
        ushort4 h;
        h.x = f2bf(v.x); h.y = f2bf(v.y); h.z = f2bf(v.z); h.w = f2bf(v.w);
        *(ushort4*)swzPtr((c4 < 64) ? sm.s.wl0 : sm.s.wl1, i, (c4 & 63) << 1) = h;
    }
    for (int u = t; u < 1024; u += 256) {
        const int i = u >> 4, cb = (u & 15) << 4;
        *(uint4*)swzPtr((cb < 128) ? sm.s.ob0 : sm.s.ob1, i, cb & 127) =
            *(const uint4*)(Ob + ((size_t)((b << 12) + n0 + i) << 7) + (cb >> 1));
    }
    __syncthreads();
    const int arow = (w << 4) + lo;
    const bf16x8 af00 = *(const bf16x8*)swzPtr(sm.s.wl0, arow, hi << 4);
    const bf16x8 af01 = *(const bf16x8*)swzPtr(sm.s.wl0, arow, 64 + (hi << 4));
    const bf16x8 af10 = *(const bf16x8*)swzPtr(sm.s.wl1, arow, hi << 4);
    const bf16x8 af11 = *(const bf16x8*)swzPtr(sm.s.wl1, arow, 64 + (hi << 4));
    f32x4 acc[4];
    #pragma unroll
    for (int ti = 0; ti < 4; ++ti) {
        const int brow = (ti << 4) + lo;
        f32x4 z = (f32x4){0.f, 0.f, 0.f, 0.f};
        z = __builtin_amdgcn_mfma_f32_16x16x32_bf16(af00, *(const bf16x8*)swzPtr(sm.s.ob0, brow, hi << 4), z, 0, 0, 0);
        z = __builtin_amdgcn_mfma_f32_16x16x32_bf16(af01, *(const bf16x8*)swzPtr(sm.s.ob0, brow, 64 + (hi << 4)), z, 0, 0, 0);
        z = __builtin_amdgcn_mfma_f32_16x16x32_bf16(af10, *(const bf16x8*)swzPtr(sm.s.ob1, brow, hi << 4), z, 0, 0, 0);
        acc[ti] = __builtin_amdgcn_mfma_f32_16x16x32_bf16(af11, *(const bf16x8*)swzPtr(sm.s.ob1, brow, 64 + (hi << 4)), z, 0, 0, 0);
    }
    __syncthreads();
    #pragma unroll
    for (int ti = 0; ti < 4; ++ti)
        #pragma unroll
        for (int r = 0; r < 4; ++r) {
            const int co = (w << 4) + (hi << 2) + r;
            const int n  = (ti << 4) + lo;
            sm.tr[(co << 6) + (n ^ (((co >> 2) & 3) << 2))] = acc[ti][r];
        }
    __syncthreads();
    const float g = gamma_p[0];
    for (int u = t; u < 1024; u += 256) {
        const int co = u >> 4, n4 = (u & 15) << 2;
        const float4 av = *(const float4*)&sm.tr[(co << 6) + (n4 ^ (((co >> 2) & 3) << 2))];
        const int o = co0 + co;
        const size_t off = ((size_t)(b * C_IN + o) << 12) + n0 + n4;
        const float4 xv = *(const float4*)(x + off);
        const float bias = bo[o];
        float4 rs;
        rs.x = xv.x + g * (av.x + bias);
        rs.y = xv.y + g * (av.y + bias);
        rs.z = xv.z + g * (av.z + bias);
        rs.w = xv.w + g * (av.w + bias);
        *(float4*)(out + off) = rs;
    }
}

extern "C" void kernel_launch(void* const* d_in, const int* in_sizes, int n_in,
                              void* d_out, int out_size, void* d_ws, size_t ws_size,
                              hipStream_t stream) {
    (void)in_sizes; (void)n_in; (void)out_size; (void)ws_size;
    const float* x  = (const float*)d_in[0];
    const float* Wq = (const float*)d_in[1];
    const float* bq = (const float*)d_in[2];
    const float* Wk = (const float*)d_in[3];
    const float* bk = (const float*)d_in[4];
    const float* Wv = (const float*)d_in[5];
    const float* bv = (const float*)d_in[6];
    const float* Wo = (const float*)d_in[7];
    const float* bo = (const float*)d_in[8];
    const float* gm = (const float*)d_in[9];
    float* out = (float*)d_out;
    // ws layout (bytes): [0,16M): xb bf16 (K0->K1) ALIASED with po bf16 (K2->K2b)
    //   then Qb 2M | Kb 2M | Vb 4M | pm 256K | pl 256K | Ob 4M   (~28.5 MB total)
    u16* xb = (u16*)d_ws;
    u16* po = (u16*)d_ws;                        // alias: xb dead after K1
    u16* Qb = xb + (size_t)8 * 1024 * 1024;
    u16* Kb = Qb + (size_t)4 * N_SP * C_QK;
    u16* Vb = Kb + (size_t)4 * N_SP * C_QK;
    float* pm = (float*)(Vb + (size_t)4 * C_V * N_SP);
    float* pl = pm + 512 * 128;
    u16* Ob = (u16*)(pl + 512 * 128);
    transpose_kernel<<<2048, 256, 0, stream>>>(x, xb);
    qkv_kernel<<<1024, 256, 0, stream>>>(xb, Wq, bq, Wk, bk, Wv, bv, Qb, Kb, Vb);
    attn_kernel<<<512, 256, 0, stream>>>(Qb, Kb, Vb, po, pm, pl);
    combine_kernel<<<128, 256, 0, stream>>>(po, pm, pl, Ob);
    proj_kernel<<<2048, 256, 0, stream>>>(Ob, Wo, bo, x, gm, out);
}

// Round 6
// 113.099 us; speedup vs baseline: 8.2280x; 1.0044x over previous
//
#include <hip/hip_runtime.h>
#include <cstdint>
#include <cstddef>

#define N_SP 4096
#define C_IN 512
#define C_QK 64
#define C_V  128
#define LOG2E 1.4426950408889634f

typedef unsigned short u16;
typedef __attribute__((ext_vector_type(8))) short bf16x8;
typedef __attribute__((ext_vector_type(4))) float f32x4;
typedef __attribute__((ext_vector_type(16))) float f32x16;

__device__ __forceinline__ u16 f2bf(float f) {
    union { float f; uint32_t u; } x; x.f = f;
    const uint32_t r = x.u + 0x7fffu + ((x.u >> 16) & 1u);
    return (u16)(r >> 16);
}
__device__ __forceinline__ float bf2f(u16 b) {
    union { uint32_t u; float f; } x; x.u = ((uint32_t)b) << 16;
    return x.f;
}

// Swizzled pointer into a 128-byte-row LDS tile: byte ^= (row&7)<<4.
__device__ __forceinline__ void* swzPtr(const void* base, int row, int colByte) {
    return (char*)base + row * 128 + (colByte ^ ((row & 7) << 4));
}

// async global->LDS, 16B per lane; LDS dest is wave-uniform base + lane*16.
__device__ __forceinline__ void gl16(const u16* g, u16* l) {
    __builtin_amdgcn_global_load_lds(
        (const __attribute__((address_space(1))) void*)g,
        (__attribute__((address_space(3))) void*)l, 16, 0, 0);
}

// ---------------- K0: transpose-convert x[b][c][n] f32 -> xb[b][n][c] bf16 ----
__global__ __launch_bounds__(256) void transpose_kernel(
    const float* __restrict__ x, u16* __restrict__ xb)
{
    __shared__ u16 ts[64 * 64];
    const int t = threadIdx.x;
    const int b  = blockIdx.x & 3;
    const int cc = (blockIdx.x >> 2) & 7;
    const int nc = blockIdx.x >> 5;
    const int c0 = cc << 6, n0 = nc << 6;
    const float* xs = x + ((size_t)(b * C_IN + c0) << 12) + n0;
    for (int u = t; u < 1024; u += 256) {
        const int c = u >> 4, nq = (u & 15) << 2;
        const float4 v = *(const float4*)(xs + ((size_t)c << 12) + nq);
        ushort4 h;
        h.x = f2bf(v.x); h.y = f2bf(v.y); h.z = f2bf(v.z); h.w = f2bf(v.w);
        *(ushort4*)((char*)ts + c * 128 + ((nq << 1) ^ (((c >> 3) & 7) << 4))) = h;
    }
    __syncthreads();
    for (int u = t; u < 512; u += 256) {
        const int n = u >> 3, cg = u & 7;
        u16 pk[8];
        #pragma unroll
        for (int j = 0; j < 8; ++j) {
            const int c = (cg << 3) + j;
            pk[j] = *(const u16*)((char*)ts + c * 128 + ((n << 1) ^ (cg << 4)));
        }
        *(ushort4*)(xb + ((size_t)((b << 12) + n0 + n) << 9) + c0 + (cg << 3)) =
            *(ushort4*)&pk[0];
        *(ushort4*)(xb + ((size_t)((b << 12) + n0 + n) << 9) + c0 + (cg << 3) + 4) =
            *(ushort4*)&pk[4];
    }
}

// ---------------- K1: QKV projection, bf16 MFMA ----------------
// Q output is pre-scaled by log2e (attention softmax runs in exp2 domain).
__global__ __launch_bounds__(256) void qkv_kernel(
    const u16* __restrict__ xb,
    const float* __restrict__ Wq, const float* __restrict__ bq,
    const float* __restrict__ Wk, const float* __restrict__ bk,
    const float* __restrict__ Wv, const float* __restrict__ bv,
    u16* __restrict__ Qb, u16* __restrict__ Kb, u16* __restrict__ Vb)
{
    __shared__ u16 wt[64 * 64];   // W chunk  [o][64 c]
    __shared__ u16 xt[64 * 64];   // xb chunk [n][64 c]
    const int t = threadIdx.x;
    const int l = t & 63, w = t >> 6;
    const int lo = l & 15, hi = l >> 4;
    const int b  = blockIdx.x & 3;
    const int ot = (blockIdx.x >> 2) & 3;
    const int n0 = (blockIdx.x >> 4) << 6;
    const float* Wbase = (ot == 0) ? Wq : (ot == 1) ? Wk : (Wv + ((ot - 2) << 6) * C_IN);
    f32x4 acc[4];
    #pragma unroll
    for (int ti = 0; ti < 4; ++ti) acc[ti] = (f32x4){0.f, 0.f, 0.f, 0.f};

    for (int cc = 0; cc < 8; ++cc) {
        const int c0 = cc << 6;
        for (int u = t; u < 1024; u += 256) {      // W rows -> bf16
            const int i = u >> 4, c4 = (u & 15) << 2;
            const float4 v = *(const float4*)(Wbase + (size_t)i * C_IN + c0 + c4);
            ushort4 h;
            h.x = f2bf(v.x); h.y = f2bf(v.y); h.z = f2bf(v.z); h.w = f2bf(v.w);
            *(ushort4*)swzPtr(wt, i, c4 << 1) = h;
        }
        for (int u = t; u < 512; u += 256) {       // xb rows (already bf16)
            const int i = u >> 3, cb = (u & 7) << 4;
            *(uint4*)swzPtr(xt, i, cb) =
                *(const uint4*)(xb + ((size_t)((b << 12) + n0 + i) << 9) + c0 + (cb >> 1));
        }
        __syncthreads();
        if (ot < 2) {
            const bf16x8 af0 = *(const bf16x8*)swzPtr(xt, (w << 4) + lo, hi << 4);
            const bf16x8 af1 = *(const bf16x8*)swzPtr(xt, (w << 4) + lo, 64 + (hi << 4));
            #pragma unroll
            for (int ti = 0; ti < 4; ++ti) {
                const bf16x8 bf0 = *(const bf16x8*)swzPtr(wt, (ti << 4) + lo, hi << 4);
                const bf16x8 bf1 = *(const bf16x8*)swzPtr(wt, (ti << 4) + lo, 64 + (hi << 4));
                acc[ti] = __builtin_amdgcn_mfma_f32_16x16x32_bf16(af0, bf0, acc[ti], 0, 0, 0);
                acc[ti] = __builtin_amdgcn_mfma_f32_16x16x32_bf16(af1, bf1, acc[ti], 0, 0, 0);
            }
        } else {
            const bf16x8 af0 = *(const bf16x8*)swzPtr(wt, (w << 4) + lo, hi << 4);
            const bf16x8 af1 = *(const bf16x8*)swzPtr(wt, (w << 4) + lo, 64 + (hi << 4));
            #pragma unroll
            for (int ti = 0; ti < 4; ++ti) {
                const bf16x8 bf0 = *(const bf16x8*)swzPtr(xt, (ti << 4) + lo, hi << 4);
                const bf16x8 bf1 = *(const bf16x8*)swzPtr(xt, (ti << 4) + lo, 64 + (hi << 4));
                acc[ti] = __builtin_amdgcn_mfma_f32_16x16x32_bf16(af0, bf0, acc[ti], 0, 0, 0);
                acc[ti] = __builtin_amdgcn_mfma_f32_16x16x32_bf16(af1, bf1, acc[ti], 0, 0, 0);
            }
        }
        __syncthreads();
    }
    if (ot < 2) {   // D row = n_local, col = o_local -> [n][64ch]
        const float* bias_base = (ot == 0) ? bq : bk;
        u16* dst = (ot == 0) ? Qb : Kb;
        const float sc = (ot == 0) ? LOG2E : 1.0f;
        #pragma unroll
        for (int ti = 0; ti < 4; ++ti) {
            const float bias = bias_base[(ti << 4) + lo];
            #pragma unroll
            for (int r = 0; r < 4; ++r) {
                const int nrow = (w << 4) + (hi << 2) + r;
                dst[((size_t)((b << 12) + n0 + nrow) << 6) + (ti << 4) + lo] =
                    f2bf((acc[ti][r] + bias) * sc);
            }
        }
    } else {        // D row = cv_local, col = n_local -> [cv][n]
        #pragma unroll
        for (int r = 0; r < 4; ++r) {
            const int cv = ((ot - 2) << 6) + (w << 4) + (hi << 2) + r;
            const float bias = bv[cv];
            #pragma unroll
            for (int ti = 0; ti < 4; ++ti)
                Vb[((size_t)(b * C_V + cv) << 12) + n0 + (ti << 4) + lo] =
                    f2bf(acc[ti][r] + bias);
        }
    }
}

// ================= K2: software-pipelined swapped-32x32 flash attention ======
// Block: 128 q (4 waves x 32), KV-split x4, 16 key-tiles of 64.
// Iter t: [vmcnt(4); s_barrier] [issue K/V(t+2)] [S(t+1) MFMA] [softmax(t) VALU]
// [PV(t) MFMA]. K dbuf, V tbuf; counted vmcnt keeps prefetch in flight across
// the raw barrier (no __syncthreads full drain). Softmax in exp2 domain,
// defer-max, P->bf16 via cvt_pk, 8-shfl P^T exchange, l-sum shfl deferred.

__device__ __forceinline__ void stageK(const u16* kbase, int m, u16* kdst,
                                       int w, int l, int colOff) {
    #pragma unroll
    for (int i = 0; i < 2; ++i) {
        const int kr = (w << 4) + (i << 3);
        gl16(kbase + ((size_t)(m + kr + (l >> 3)) << 6) + colOff, kdst + (kr << 6));
    }
}
__device__ __forceinline__ void stageV(const u16* vbase, int m, u16* vdst,
                                       int w, int l, int colOff) {
    #pragma unroll
    for (int i = 0; i < 4; ++i) {
        const int cv = (w << 5) + (i << 3);
        gl16(vbase + ((size_t)(cv + (l >> 3)) << 12) + m + colOff, vdst + (cv << 6));
    }
}
__device__ __forceinline__ void computeS(const u16* kbuf, const bf16x8* qf,
                                         int l31, int h, f32x16& s0, f32x16& s1) {
    #pragma unroll
    for (int i = 0; i < 16; ++i) { s0[i] = 0.f; s1[i] = 0.f; }
    __builtin_amdgcn_s_setprio(1);
    #pragma unroll
    for (int ks = 0; ks < 4; ++ks) {
        const bf16x8 k0 = *(const bf16x8*)swzPtr(kbuf, l31,      (h << 4) + (ks << 5));
        const bf16x8 k1 = *(const bf16x8*)swzPtr(kbuf, 32 + l31, (h << 4) + (ks << 5));
        s0 = __builtin_amdgcn_mfma_f32_32x32x16_bf16(k0, qf[ks], s0, 0, 0, 0);
        s1 = __builtin_amdgcn_mfma_f32_32x32x16_bf16(k1, qf[ks], s1, 0, 0, 0);
    }
    __builtin_amdgcn_s_setprio(0);
}
__device__ __forceinline__ void softmaxPV(f32x16& sa0, f32x16& sa1, const u16* vbuf,
                                          float& m_run, float& lsum,
                                          f32x16 (&oacc)[4], int l31, int h) {
    float mx[8];
    #pragma unroll
    for (int i = 0; i < 8; ++i)
        mx[i] = fmaxf(fmaxf(sa0[i], sa0[i + 8]), fmaxf(sa1[i], sa1[i + 8]));
    #pragma unroll
    for (int i = 0; i < 4; ++i) mx[i] = fmaxf(mx[i], mx[i + 4]);
    mx[0] = fmaxf(fmaxf(mx[0], mx[1]), fmaxf(mx[2], mx[3]));
    const float pmax = fmaxf(mx[0], __shfl_xor(mx[0], 32));
    if (!__all(pmax <= m_run + 8.0f)) {     // defer-max (THR=8)
        const float nm = fmaxf(m_run, pmax);
        const float al = exp2f(m_run - nm);
        m_run = nm;
        #pragma unroll
        for (int tj = 0; tj < 4; ++tj)
            #pragma unroll
            for (int i = 0; i < 16; ++i) oacc[tj][i] *= al;
        lsum *= al;
    }
    float p0[16], p1[16];
    #pragma unroll
    for (int i = 0; i < 16; ++i) {
        p0[i] = exp2f(sa0[i] - m_run);
        p1[i] = exp2f(sa1[i] - m_run);
    }
    float sm8[8];
    #pragma unroll
    for (int i = 0; i < 8; ++i) sm8[i] = (p0[i] + p0[i + 8]) + (p1[i] + p1[i + 8]);
    #pragma unroll
    for (int i = 0; i < 4; ++i) sm8[i] += sm8[i + 4];
    lsum += (sm8[0] + sm8[1]) + (sm8[2] + sm8[3]);   // own-half sum; partner at epilogue
    uint32_t P2[2][4][2];
    #pragma unroll
    for (int g = 0; g < 4; ++g)
        #pragma unroll
        for (int pr = 0; pr < 2; ++pr) {
            asm("v_cvt_pk_bf16_f32 %0, %1, %2"
                : "=v"(P2[0][g][pr]) : "v"(p0[4 * g + 2 * pr]), "v"(p0[4 * g + 2 * pr + 1]));
            asm("v_cvt_pk_bf16_f32 %0, %1, %2"
                : "=v"(P2[1][g][pr]) : "v"(p1[4 * g + 2 * pr]), "v"(p1[4 * g + 2 * pr + 1]));
        }
    bf16x8 pf[4];
    #pragma unroll
    for (int ks = 0; ks < 4; ++ks) {
        const int iE = ks << 1, iO = iE + 1;
        uint32_t fr[4];
        #pragma unroll
        for (int pr = 0; pr < 2; ++pr) {
            const uint32_t X = P2[iE >> 2][iE & 3][pr];
            const uint32_t Y = P2[iO >> 2][iO & 3][pr];
            const uint32_t send = h ? X : Y;                 // partner needs this
            const uint32_t recv = (uint32_t)__shfl_xor((int)send, 32);
            fr[pr]     = h ? recv : X;
            fr[2 + pr] = h ? Y : recv;
        }
        pf[ks] = *(bf16x8*)fr;
    }
    __builtin_amdgcn_s_setprio(1);
    #pragma unroll
    for (int tj = 0; tj < 4; ++tj)
        #pragma unroll
        for (int ks = 0; ks < 4; ++ks) {
            const bf16x8 vf =
                *(const bf16x8*)swzPtr(vbuf, (tj << 5) + l31, (h << 4) + (ks << 5));
            oacc[tj] = __builtin_amdgcn_mfma_f32_32x32x16_bf16(vf, pf[ks], oacc[tj], 0, 0, 0);
        }
    __builtin_amdgcn_s_setprio(0);
}

template<bool ISSUE>
__device__ __forceinline__ void attn_iter(
    int t, const u16* kbase, const u16* vbase, int m0base,
    u16* k_read, u16* k_write, u16* v_cur, u16* v_fly,
    const bf16x8* qf, f32x16& c0, f32x16& c1, f32x16& n0v, f32x16& n1v,
    float& m_run, float& lsum, f32x16 (&oacc)[4],
    int w, int l, int l31, int h, int colOff)
{
    asm volatile("s_waitcnt vmcnt(4)" ::: "memory");
    __builtin_amdgcn_s_barrier();
    __builtin_amdgcn_sched_barrier(0);
    if (ISSUE) {
        const int m2 = m0base + ((t + 2) << 6);
        stageK(kbase, m2, k_write, w, l, colOff);
        stageV(vbase, m2, v_fly, w, l, colOff);
    }
    computeS(k_read, qf, l31, h, n0v, n1v);          // S(t+1)
    softmaxPV(c0, c1, v_cur, m_run, lsum, oacc, l31, h);  // tile t
}

__global__ __launch_bounds__(256, 2) void attn_kernel(
    const u16* __restrict__ Qb, const u16* __restrict__ Kb,
    const u16* __restrict__ Vb, u16* __restrict__ po,
    float* __restrict__ pm, float* __restrict__ pl)
{
    __shared__ u16 ksm[2][64 * 64];    // 16 KB  [key][64ch]
    __shared__ u16 vsm[3][128 * 64];   // 48 KB  [cv][64key]
    const int t = threadIdx.x;
    const int l = t & 63, w = t >> 6;          // 4 waves
    const int l31 = l & 31, h = l >> 5;
    const int b = blockIdx.x & 3;
    const int s = (blockIdx.x >> 2) & 3;
    const int qc = blockIdx.x >> 4;
    const int n0 = qc << 7;                    // 128 q per block
    const int colOff = ((l & 7) ^ (l >> 3)) << 3;   // pre-swizzled source col
    const u16* kbase = Kb + ((size_t)b << 18);
    const u16* vbase = Vb + ((size_t)(b * C_V) << 12);
    const int m0base = s << 10;

    // Q B-frags straight from global (row = this lane's query)
    const u16* qrow_p = Qb + ((size_t)((b << 12) + n0 + (w << 5) + l31) << 6) + (h << 3);
    bf16x8 qf[4];
    #pragma unroll
    for (int ks = 0; ks < 4; ++ks) qf[ks] = *(const bf16x8*)(qrow_p + (ks << 4));

    // prologue: stage K0,V0,K1,V1 (order matters for vmcnt counting)
    stageK(kbase, m0base,      ksm[0], w, l, colOff);
    stageV(vbase, m0base,      vsm[0], w, l, colOff);
    stageK(kbase, m0base + 64, ksm[1], w, l, colOff);
    stageV(vbase, m0base + 64, vsm[1], w, l, colOff);

    float m_run = -1e30f, lsum = 0.f;
    f32x16 oacc[4];
    #pragma unroll
    for (int tj = 0; tj < 4; ++tj)
        #pragma unroll
        for (int i = 0; i < 16; ++i) oacc[tj][i] = 0.f;

    asm volatile("s_waitcnt vmcnt(10)" ::: "memory");   // K0 (+qf) landed
    __builtin_amdgcn_s_barrier();
    __builtin_amdgcn_sched_barrier(0);

    f32x16 A0, A1, B0, B1;
    computeS(ksm[0], qf, l31, h, A0, A1);    // S(0)

    u16 *kr_ = ksm[1], *kw_ = ksm[0];
    u16 *vc = vsm[0], *vn = vsm[1], *vf = vsm[2];
    for (int tt = 0; tt < 14; tt += 2) {
        attn_iter<true>(tt, kbase, vbase, m0base, kr_, kw_, vc, vf,
                        qf, A0, A1, B0, B1, m_run, lsum, oacc, w, l, l31, h, colOff);
        { u16* tk = kr_; kr_ = kw_; kw_ = tk; }
        { u16* tv = vc; vc = vn; vn = vf; vf = tv; }
        attn_iter<true>(tt + 1, kbase, vbase, m0base, kr_, kw_, vc, vf,
                        qf, B0, B1, A0, A1, m_run, lsum, oacc, w, l, l31, h, colOff);
        { u16* tk = kr_; kr_ = kw_; kw_ = tk; }
        { u16* tv = vc; vc = vn; vn = vf; vf = tv; }
    }
    attn_iter<false>(14, kbase, vbase, m0base, kr_, kw_, vc, vf,
                     qf, A0, A1, B0, B1, m_run, lsum, oacc, w, l, l31, h, colOff);
    { u16* tv = vc; vc = vn; vn = vf; vf = tv; }
    asm volatile("s_waitcnt vmcnt(0)" ::: "memory");
    __builtin_amdgcn_s_barrier();
    __builtin_amdgcn_sched_barrier(0);
    softmaxPV(B0, B1, vc, m_run, lsum, oacc, l31, h);   // tile 15

    // epilogue: unnormalized O^T partials (bf16) + stats
    lsum += __shfl_xor(lsum, 32);            // deferred cross-half sum
    u16* pod = po + ((size_t)blockIdx.x << 14);   // [128 cv][128 q]
    #pragma unroll
    for (int tj = 0; tj < 4; ++tj)
        #pragma unroll
        for (int r = 0; r < 16; ++r) {
            const int cv = (tj << 5) + (r & 3) + ((r >> 2) << 3) + (h << 2);
            pod[(cv << 7) + (w << 5) + l31] = f2bf(oacc[tj][r]);
        }
    if (h == 0) {
        pm[(blockIdx.x << 7) + (w << 5) + l31] = m_run;
        pl[(blockIdx.x << 7) + (w << 5) + l31] = lsum;
    }
}

// ---------------- K2b: flash combine (4 splits) -> Ob[b][n][cv] bf16 ----------
__global__ __launch_bounds__(256) void combine_kernel(
    const u16* __restrict__ po, const float* __restrict__ pm,
    const float* __restrict__ pl, u16* __restrict__ Ob)
{
    __shared__ float fs[4][128];
    __shared__ float invl[128];
    __shared__ float tr[64][132];
    const int t = threadIdx.x;
    const int b = blockIdx.x & 3;
    const int qc = blockIdx.x >> 2;            // 0..31 (128-q chunks)
    int slot[4];
    #pragma unroll
    for (int s = 0; s < 4; ++s) slot[s] = b + (s << 2) + (qc << 4);
    if (t < 128) {
        const float m0 = pm[(slot[0] << 7) + t], m1 = pm[(slot[1] << 7) + t];
        const float m2 = pm[(slot[2] << 7) + t], m3 = pm[(slot[3] << 7) + t];
        const float mg = fmaxf(fmaxf(m0, m1), fmaxf(m2, m3));
        const float f0 = exp2f(m0 - mg), f1 = exp2f(m1 - mg);
        const float f2 = exp2f(m2 - mg), f3 = exp2f(m3 - mg);
        const float lg = pl[(slot[0] << 7) + t] * f0 + pl[(slot[1] << 7) + t] * f1 +
                         pl[(slot[2] << 7) + t] * f2 + pl[(slot[3] << 7) + t] * f3;
        fs[0][t] = f0; fs[1][t] = f1; fs[2][t] = f2; fs[3][t] = f3;
        invl[t] = 1.0f / lg;
    }
    __syncthreads();
    #pragma unroll
    for (int qh = 0; qh < 2; ++qh) {
        for (int u = t; u < 2048; u += 256) {           // accumulate -> LDS [q][cv]
            const int cv = u >> 4, q4 = (u & 15) << 2;
            const int q = (qh << 6) + q4;
            float a0 = 0.f, a1 = 0.f, a2 = 0.f, a3 = 0.f;
            #pragma unroll
            for (int s = 0; s < 4; ++s) {
                const ushort4 hv =
                    *(const ushort4*)(po + ((size_t)slot[s] << 14) + (cv << 7) + q);
                a0 += bf2f(hv.x) * fs[s][q];
                a1 += bf2f(hv.y) * fs[s][q + 1];
                a2 += bf2f(hv.z) * fs[s][q + 2];
                a3 += bf2f(hv.w) * fs[s][q + 3];
            }
            tr[q4 + 0][cv] = a0 * invl[q];
            tr[q4 + 1][cv] = a1 * invl[q + 1];
            tr[q4 + 2][cv] = a2 * invl[q + 2];
            tr[q4 + 3][cv] = a3 * invl[q + 3];
        }
        __syncthreads();
        for (int u = t; u < 2048; u += 256) {           // write [n][cv]
            const int q = u >> 5, c4 = (u & 31) << 2;
            const float4 v = *(const float4*)&tr[q][c4];
            ushort4 o;
            o.x = f2bf(v.x); o.y = f2bf(v.y); o.z = f2bf(v.z); o.w = f2bf(v.w);
            const int n = (qc << 7) + (qh << 6) + q;
            *(ushort4*)(Ob + ((size_t)((b << 12) + n) << 7) + c4) = o;
        }
        __syncthreads();
    }
}

// ---------------- K3: output projection + residual, bf16 MFMA ----------------
__global__ __launch_bounds__(256) void proj_kernel(
    const u16* __restrict__ Ob, const float* __restrict__ Wo,
    const float* __restrict__ bo, const float* __restrict__ x,
    const float* __restrict__ gamma_p, float* __restrict__ out)
{
    __shared__ union {
        struct { u16 wl0[64 * 64]; u16 wl1[64 * 64]; u16 ob0[64 * 64]; u16 ob1[64 * 64]; } s;
        float tr[64 * 64];
    } sm;
    const int t = threadIdx.x;
    const int l = t & 63, w = t >> 6;
    const int lo = l & 15, hi = l >> 4;
    const int b  = blockIdx.x & 3;
    const int co0 = ((blockIdx.x >> 2) & 7) << 6;
    const int n0  = (blockIdx.x >> 5) << 6;
    for (int u = t; u < 2048; u += 256) {
        const int i = u >> 5, c4 = (u & 31) << 2;
        const float4 v = *(const float4*)(Wo + (size_t)(co0 + i) * C_V + c4);
        ushort4 h;
        h.x = f2bf(v.x); h.y = f2bf(v.y); h.z = f2bf(v.z); h.w = f2bf(v.w);
        *(ushort4*)swzPtr((c4 < 64) ? sm.s.wl0 : sm.s.wl1, i, (c4 & 63) << 1) = h;
    }
    for (int u = t; u < 1024; u += 256) {
        const int i = u >> 4, cb = (u & 15) << 4;
        *(uint4*)swzPtr((cb < 128) ? sm.s.ob0 : sm.s.ob1, i, cb & 127) =
            *(const uint4*)(Ob + ((size_t)((b << 12) + n0 + i) << 7) + (cb >> 1));
    }
    __syncthreads();
    const int arow = (w << 4) + lo;
    const bf16x8 af00 = *(const bf16x8*)swzPtr(sm.s.wl0, arow, hi << 4);
    const bf16x8 af01 = *(const bf16x8*)swzPtr(sm.s.wl0, arow, 64 + (hi << 4));
    const bf16x8 af10 = *(const bf16x8*)swzPtr(sm.s.wl1, arow, hi << 4);
    const bf16x8 af11 = *(const bf16x8*)swzPtr(sm.s.wl1, arow, 64 + (hi << 4));
    f32x4 acc[4];
    #pragma unroll
    for (int ti = 0; ti < 4; ++ti) {
        const int brow = (ti << 4) + lo;
        f32x4 z = (f32x4){0.f, 0.f, 0.f, 0.f};
        z = __builtin_amdgcn_mfma_f32_16x16x32_bf16(af00, *(const bf16x8*)swzPtr(sm.s.ob0, brow, hi << 4), z, 0, 0, 0);
        z = __builtin_amdgcn_mfma_f32_16x16x32_bf16(af01, *(const bf16x8*)swzPtr(sm.s.ob0, brow, 64 + (hi << 4)), z, 0, 0, 0);
        z = __builtin_amdgcn_mfma_f32_16x16x32_bf16(af10, *(const bf16x8*)swzPtr(sm.s.ob1, brow, hi << 4), z, 0, 0, 0);
        acc[ti] = __builtin_amdgcn_mfma_f32_16x16x32_bf16(af11, *(const bf16x8*)swzPtr(sm.s.ob1, brow, 64 + (hi << 4)), z, 0, 0, 0);
    }
    __syncthreads();
    #pragma unroll
    for (int ti = 0; ti < 4; ++ti)
        #pragma unroll
        for (int r = 0; r < 4; ++r) {
            const int co = (w << 4) + (hi << 2) + r;
            const int n  = (ti << 4) + lo;
            sm.tr[(co << 6) + (n ^ (((co >> 2) & 3) << 2))] = acc[ti][r];
        }
    __syncthreads();
    const float g = gamma_p[0];
    for (int u = t; u < 1024; u += 256) {
        const int co = u >> 4, n4 = (u & 15) << 2;
        const float4 av = *(const float4*)&sm.tr[(co << 6) + (n4 ^ (((co >> 2) & 3) << 2))];
        const int o = co0 + co;
        const size_t off = ((size_t)(b * C_IN + o) << 12) + n0 + n4;
        const float4 xv = *(const float4*)(x + off);
        const float bias = bo[o];
        float4 rs;
        rs.x = xv.x + g * (av.x + bias);
        rs.y = xv.y + g * (av.y + bias);
        rs.z = xv.z + g * (av.z + bias);
        rs.w = xv.w + g * (av.w + bias);
        *(float4*)(out + off) = rs;
    }
}

extern "C" void kernel_launch(void* const* d_in, const int* in_sizes, int n_in,
                              void* d_out, int out_size, void* d_ws, size_t ws_size,
                              hipStream_t stream) {
    (void)in_sizes; (void)n_in; (void)out_size; (void)ws_size;
    const float* x  = (const float*)d_in[0];
    const float* Wq = (const float*)d_in[1];
    const float* bq = (const float*)d_in[2];
    const float* Wk = (const float*)d_in[3];
    const float* bk = (const float*)d_in[4];
    const float* Wv = (const float*)d_in[5];
    const float* bv = (const float*)d_in[6];
    const float* Wo = (const float*)d_in[7];
    const float* bo = (const float*)d_in[8];
    const float* gm = (const float*)d_in[9];
    float* out = (float*)d_out;
    // ws layout (bytes): [0,16M): xb bf16 (K0->K1) ALIASED with po bf16 (K2->K2b)
    //   then Qb 2M | Kb 2M | Vb 4M | pm 256K | pl 256K | Ob 4M   (~28.5 MB total)
    u16* xb = (u16*)d_ws;
    u16* po = (u16*)d_ws;                        // alias: xb dead after K1
    u16* Qb = xb + (size_t)8 * 1024 * 1024;
    u16* Kb = Qb + (size_t)4 * N_SP * C_QK;
    u16* Vb = Kb + (size_t)4 * N_SP * C_QK;
    float* pm = (float*)(Vb + (size_t)4 * C_V * N_SP);
    float* pl = pm + 512 * 128;
    u16* Ob = (u16*)(pl + 512 * 128);
    transpose_kernel<<<2048, 256, 0, stream>>>(x, xb);
    qkv_kernel<<<1024, 256, 0, stream>>>(xb, Wq, bq, Wk, bk, Wv, bv, Qb, Kb, Vb);
    attn_kernel<<<512, 256, 0, stream>>>(Qb, Kb, Vb, po, pm, pl);
    combine_kernel<<<128, 256, 0, stream>>>(po, pm, pl, Ob);
    proj_kernel<<<2048, 256, 0, stream>>>(Ob, Wo, bo, x, gm, out);
}